// Round 18
// baseline (344.026 us; speedup 1.0000x reference)
//
#include <hip/hip_runtime.h>

typedef unsigned short u16;
typedef unsigned int u32;
typedef __attribute__((ext_vector_type(8))) __bf16 bf16x8;
typedef __attribute__((ext_vector_type(8))) u16 u16x8;
typedef __attribute__((ext_vector_type(4))) float f32x4;
typedef __attribute__((ext_vector_type(2))) u32 u32x2;

// padded plane: [b][258][258][16ic]; 1-pixel zero border for DMA staging
static constexpr size_t PSP = (size_t)8 * 258 * 258 * 16;  // u16 elems per plane

#define GPTR(p) ((const __attribute__((address_space(1))) void*)(p))
#define LPTR(p) ((__attribute__((address_space(3))) void*)(p))

__device__ __forceinline__ u16 f2bf(float f) {
  u32 u = __builtin_bit_cast(u32, f);
  u = (u + 0x7FFFu + ((u >> 16) & 1u)) >> 16;
  return (u16)u;
}

__device__ __forceinline__ f32x4 mfma16(bf16x8 a, bf16x8 b, f32x4 c) {
  return __builtin_amdgcn_mfma_f32_16x16x32_bf16(a, b, c, 0, 0, 0);
}

// ---------- zero the 1-pixel border of a 4-plane padded array ----------
__global__ void k_zero_border(u16* __restrict__ base) {
  int idx = blockIdx.x * 256 + threadIdx.x;
  if (idx >= 4 * 8 * 1028) return;
  int p = idx / (8 * 1028), r = idx - p * (8 * 1028);
  int b = r / 1028, e = r - b * 1028;
  int y, x;
  if (e < 258) { y = 0; x = e; }
  else if (e < 516) { y = 257; x = e - 258; }
  else { int e2 = e - 516; y = 1 + (e2 >> 1); x = (e2 & 1) * 257; }
  u16* d = base + (size_t)p * PSP + (((size_t)b * 258 + y) * 258 + x) * 16;
  u16x8 z = (u16x8)0;
  *(u16x8*)d = z;
  *(u16x8*)(d + 8) = z;
}

// ---------- NCHW f32 -> 4-plane padded bf16: [p][b][1+y][1+x][16ic] ----------
__global__ __launch_bounds__(256) void k_tr(const float* __restrict__ x,
                                            u16* __restrict__ xh) {
  __shared__ float t[64][33];
  const int b = blockIdx.z, y = blockIdx.y, x0 = blockIdx.x * 32;
  const int tid = threadIdx.x;
  {
    int ic = tid >> 2, xo = (tid & 3) * 8;
    const float* s = x + (((size_t)b * 64 + ic) * 256 + y) * 256 + x0 + xo;
    f32x4 v0 = *(const f32x4*)s;
    f32x4 v1 = *(const f32x4*)(s + 4);
#pragma unroll
    for (int j = 0; j < 4; ++j) { t[ic][xo + j] = v0[j]; t[ic][xo + 4 + j] = v1[j]; }
  }
  __syncthreads();
  {
    int xc = tid & 31, slot = tid >> 5;  // slot 0..7 -> ic0 = slot*8
    int ic0 = slot * 8;
    u16x8 v;
#pragma unroll
    for (int j = 0; j < 8; ++j) v[j] = f2bf(t[ic0 + j][xc]);
    *(u16x8*)(xh + (size_t)(slot >> 1) * PSP +
              (((size_t)b * 258 + y + 1) * 258 + x0 + xc + 1) * 16 + (slot & 1) * 8) = v;
  }
}

// ---------- conv2/3 weights: [OC][IC][3][3] f32 -> [oc][tap*IC+icp] bf16 ----------
// perm=1: input channels arrive permuted as icp = (ic&15)*2 + (ic>>4)  (IC=32)
__global__ void k_prep_cw(const float* __restrict__ src, u16* __restrict__ dst,
                          int IC, int KK2, int n, int perm) {
  int d = blockIdx.x * 256 + threadIdx.x;
  if (d >= n) return;
  int per = KK2 * IC;
  int oc = d / per, r = d - oc * per;
  int tap = r / IC, icp = r - tap * IC;
  int ic = perm ? ((icp >> 1) + (icp & 1) * 16) : icp;
  dst[d] = f2bf(src[(oc * IC + ic) * KK2 + tap]);
}

// ---------- conv1 weights: [32][64][7][7] f32 -> [8 chunks][t(52)][oc(32)][8 ic] bf16 ----------
// t-major so DMA dests are linear; taps 49..51 zero-padded; chunk h = ic h*8..h*8+7
__global__ void k_prep_cw1(const float* __restrict__ src, u16* __restrict__ dst) {
  int d = blockIdx.x * 256 + threadIdx.x;  // 8*52*32*8 = 106496
  if (d >= 106496) return;
  int h = d / 13312, r = d - h * 13312;
  int t = r >> 8, r2 = r & 255;
  int oc = r2 >> 3, i = r2 & 7;
  float v = (t < 49) ? src[(oc * 64 + h * 8 + i) * 49 + t] : 0.f;
  dst[d] = f2bf(v);
}

// ---------- HDA weights -> [b][cc(4)][oc(64)][s(5)][kq(4)][j(8)] bf16 ----------
__global__ void k_prep_hda(const float* __restrict__ dyn, const float* __restrict__ ow,
                           const float* __restrict__ share, const float* __restrict__ a_,
                           u16* __restrict__ dst, int use_a, int perm) {
  int d = blockIdx.x * 256 + threadIdx.x;  // 8*4*64*160 = 327680
  if (d >= 327680) return;
  int b = d / 40960, r = d - b * 40960;
  int cc = r / 10240, r2 = r - cc * 10240;
  int oc = r2 / 160, r3 = r2 - oc * 160;
  int s = r3 >> 5, r4 = r3 & 31;
  int kq = r4 >> 3, j = r4 & 7;
  int tap = 2 * s + (kq >> 1);
  float v = 0.f;
  if (tap < 9) {
    int icp = cc * 16 + (kq & 1) * 8 + j;
    int ic = perm ? ((icp & 3) * 16 + (icp >> 2)) : icp;
    v = (oc < 32) ? dyn[(oc * 64 + ic) * 9 + tap] * ow[((b * 32 + oc) * 64 + ic) * 9 + tap]
                  : share[((oc - 32) * 64 + ic) * 9 + tap];
    if (use_a) v *= a_[b * 64 + oc];
  }
  dst[d] = f2bf(v);
}

// ---------- cond conv1: 7x7 s2 p1 64->32, MFMA, DMA-staged A+W in LDS ----------
__global__ __launch_bounds__(256, 2) void k_cond1_mfma(const u16* __restrict__ xh,
    const u16* __restrict__ wp /*[8][52][32][8]*/, const float* __restrict__ cb,
    u16* __restrict__ dst) {
  __shared__ char lds[49152];  // [0,22528): A; [22528,49152): W
  const int wg0 = blockIdx.x;
  const int wg = ((wg0 & 7) << 6) | (wg0 >> 3);
  const int b = wg >> 6, rr = wg & 63;
  const int oh0 = (rr >> 3) << 4, ow0 = (rr & 7) << 4;
  const int tid = threadIdx.x, lane = tid & 63, wid = tid >> 6;
  const int col = lane & 15, kq = lane >> 4;
  f32x4 acc[4][2];
#pragma unroll
  for (int i = 0; i < 4; ++i)
#pragma unroll
    for (int j = 0; j < 2; ++j) acc[i][j] = 0.f;
  int pb[4];
#pragma unroll
  for (int mf = 0; mf < 4; ++mf) pb[mf] = (2 * (wid * 4 + mf)) * 37 + 2 * col;
#pragma unroll 1
  for (int h = 0; h < 8; ++h) {
    __syncthreads();
    // A DMA: granule g holds A[swz(g)]; source pre-swizzled, dest linear
#pragma unroll
    for (int it = 0; it < 6; ++it) {
      if (it < 5 || wid < 2) {
        int g = it * 256 + tid;
        int i = g ^ ((g >> 3) & 7);
        if (i >= 1406) i = 0;  // dummy granules (never read)
        int r = i / 37, cc2 = i - r * 37;
        const u16* src = xh + (size_t)(h >> 1) * PSP +
            (((size_t)b * 258 + 2 * oh0 + r) * 258 + 2 * ow0 + cc2) * 16 + (h & 1) * 8;
        __builtin_amdgcn_global_load_lds(GPTR(src),
            LPTR(lds + (it * 256 + wid * 64) * 16), 16, 0, 0);
      }
    }
    // W DMA: [t(52)][oc(32)] linear dest
#pragma unroll
    for (int it = 0; it < 7; ++it) {
      if (it < 6 || wid < 2) {
        int g = it * 256 + tid;
        int t = g >> 5, oc = g & 31;
        const u16* src = wp + h * 13312 + t * 256 + oc * 8;
        __builtin_amdgcn_global_load_lds(GPTR(src),
            LPTR(lds + 22528 + (it * 256 + wid * 64) * 16), 16, 0, 0);
      }
    }
    __syncthreads();
    __builtin_amdgcn_s_setprio(1);
#pragma unroll
    for (int s = 0; s < 13; ++s) {  // taps 4s+kq
      const int t0 = 4 * s;
      const int kh0 = t0 / 7, r7 = t0 % 7;
      int carry = (kq >= 7 - r7) ? 1 : 0;
      int kh = kh0 + carry;
      int kw = r7 + kq - carry * 7;
      int prow = kh * 37 + kw;
      bf16x8 a[4];
#pragma unroll
      for (int mf = 0; mf < 4; ++mf) {
        int pos = pb[mf] + prow;
        int g = pos ^ ((pos >> 3) & 7);
        a[mf] = __builtin_bit_cast(bf16x8, *(const u16x8*)(lds + g * 16));
      }
      bf16x8 w[2];
#pragma unroll
      for (int nf = 0; nf < 2; ++nf)
        w[nf] = __builtin_bit_cast(bf16x8,
            *(const u16x8*)(lds + 22528 + (((4 * s + kq) * 32) + nf * 16 + col) * 16));
#pragma unroll
      for (int mf = 0; mf < 4; ++mf)
#pragma unroll
        for (int nf = 0; nf < 2; ++nf) acc[mf][nf] = mfma16(a[mf], w[nf], acc[mf][nf]);
    }
    __builtin_amdgcn_s_setprio(0);
  }
  const float bv0 = cb[col], bv1 = cb[16 + col];
#pragma unroll
  for (int mf = 0; mf < 4; ++mf) {
    int oh = oh0 + wid * 4 + mf;
    if (oh >= 126) continue;
#pragma unroll
    for (int r = 0; r < 4; ++r) {
      int ow = ow0 + kq * 4 + r;
      if (ow >= 126) continue;
      u32 pack = (u32)f2bf(fmaxf(acc[mf][0][r] + bv0, 0.f)) |
                 ((u32)f2bf(fmaxf(acc[mf][1][r] + bv1, 0.f)) << 16);
      *(u32*)(dst + (((size_t)b * 126 + oh) * 126 + ow) * 32 + col * 2) = pack;
    }
  }
}

// ---------- generic stride-2 pad-1 conv (small conv2/conv3) ----------
template <int HI, int HO, int IC, int KK, int OUTF32>
__global__ __launch_bounds__(256, 4) void k_conv_s2(const u16* __restrict__ src,
    const u16* __restrict__ wgt, const float* __restrict__ bias, void* __restrict__ dst) {
  const int b = blockIdx.z;
  const int by0 = blockIdx.y * 8, bx0 = blockIdx.x * 16;
  const int tid = threadIdx.x, lane = tid & 63, wid = tid >> 6;
  const int col = lane & 15, kq = lane >> 4;
  f32x4 acc[2][2];
#pragma unroll
  for (int i = 0; i < 2; ++i)
#pragma unroll
    for (int j = 0; j < 2; ++j) acc[i][j] = 0.f;
  const u16x8 Z = (u16x8)0;
#pragma unroll
  for (int kh = 0; kh < KK; ++kh) {
#pragma unroll
    for (int kw = 0; kw < KK; ++kw) {
#pragma unroll
      for (int h = 0; h < IC / 32; ++h) {
        bf16x8 a[2];
#pragma unroll
        for (int mf = 0; mf < 2; ++mf) {
          int oh = by0 + wid * 2 + mf;
          int ih = 2 * oh - 1 + kh;
          int ix = 2 * (bx0 + col) - 1 + kw;
          int ic = h * 32 + kq * 8;
          u16x8 raw = Z;
          if ((unsigned)ih < (unsigned)HI && (unsigned)ix < (unsigned)HI)
            raw = *(const u16x8*)(src + (((size_t)b * HI + ih) * HI + ix) * IC + ic);
          a[mf] = __builtin_bit_cast(bf16x8, raw);
        }
        int k0 = (kh * KK + kw) * IC + h * 32 + kq * 8;
        bf16x8 w[2];
#pragma unroll
        for (int nf = 0; nf < 2; ++nf)
          w[nf] = __builtin_bit_cast(bf16x8,
                    *(const u16x8*)(wgt + (size_t)(nf * 16 + col) * (KK * KK * IC) + k0));
#pragma unroll
        for (int mf = 0; mf < 2; ++mf)
#pragma unroll
          for (int nf = 0; nf < 2; ++nf) acc[mf][nf] = mfma16(a[mf], w[nf], acc[mf][nf]);
      }
    }
  }
#pragma unroll
  for (int mf = 0; mf < 2; ++mf) {
    int oh = by0 + wid * 2 + mf;
    if (oh >= HO) continue;
#pragma unroll
    for (int nf = 0; nf < 2; ++nf) {
      int oc = nf * 16 + col;
      float bv = bias[oc];
#pragma unroll
      for (int r = 0; r < 4; ++r) {
        int ow = bx0 + kq * 4 + r;
        if (ow >= HO) continue;
        float v = fmaxf(acc[mf][nf][r] + bv, 0.f);
        if (OUTF32)
          ((float*)dst)[(((size_t)b * 32 + oc) * HO + oh) * HO + ow] = v;
        else
          ((u16*)dst)[(((size_t)b * HO + oh) * HO + ow) * 32 + oc] = f2bf(v);
      }
    }
  }
}

// ---------- mean over 32x32 -> cond[8*32] ----------
__global__ void k_mean(const float* __restrict__ h3, float* __restrict__ cond) {
  int bo = blockIdx.x;
  int tid = threadIdx.x;
  float s = 0.f;
  for (int i = tid; i < 1024; i += 256) s += h3[bo * 1024 + i];
  __shared__ float red[256];
  red[tid] = s;
  __syncthreads();
  for (int o = 128; o > 0; o >>= 1) {
    if (tid < o) red[tid] += red[tid + o];
    __syncthreads();
  }
  if (tid == 0) cond[bo] = red[0] * (1.f / 1024.f);
}

// ---------- FiLM fold ----------
__global__ void k_film(const float* __restrict__ cond,
                       const float* __restrict__ scale_w, const float* __restrict__ scale_b,
                       const float* __restrict__ shift_w, const float* __restrict__ shift_b,
                       const float* __restrict__ share1_b, const float* __restrict__ share2_b,
                       float* __restrict__ a_, float* __restrict__ bias1,
                       float* __restrict__ bias2) {
  int t = threadIdx.x;  // 512
  int b = t >> 6, j = t & 63;
  float s = scale_b[j], sh = shift_b[j];
  for (int k = 0; k < 32; ++k) {
    float c = cond[b * 32 + k];
    s = fmaf(c, scale_w[j * 32 + k], s);
    sh = fmaf(c, shift_w[j * 32 + k], sh);
  }
  float a = s + 1.f;
  float b0 = (j < 32) ? 0.f : share1_b[j - 32];
  a_[t] = a;
  bias1[t] = fmaf(a, b0, sh);
  bias2[t] = (j < 32) ? 0.f : share2_b[j - 32];
}

// ---------- HDA A-chunk stage (512 threads): DMA A only (704 granules) ----------
__device__ __forceinline__ void hda_stage(const u16* __restrict__ asrc,
                                          char* lb, int b, int by0, int bx0,
                                          int cc, int tid, int wid) {
  const u16* ap = asrc + (size_t)cc * PSP;
#pragma unroll
  for (int it = 0; it < 2; ++it) {
    if (it == 0 || tid < 192) {  // waves 0..2 for the tail (wave-uniform)
      int g = it * 512 + tid;
      int i = g ^ ((g >> 3) & 1);
      int pos = i >> 1, sl = i & 1;
      if (pos >= 342) { pos = 0; sl = 0; }
      int yy = pos / 18, xx = pos - yy * 18;
      const u16* src = ap + (((size_t)b * 258 + by0 + yy) * 258 + bx0 + xx) * 16 + sl * 8;
      __builtin_amdgcn_global_load_lds(GPTR(src),
          LPTR(lb + (it * 512 + wid * 64) * 16), 16, 0, 0);
    }
  }
}

// ---------- HDA conv 3x3 s1 p1 64->64, MFMA, 4 chunks of 16 ic ----------
// LDS-traffic fix: W fragments come straight from L2 (per-block W = 80KB, shared by
// 256 blocks of the batch -> L2-resident) into registers; LDS carries only A
// (2x11KB double-buffer) -> LDS bytes/FLOP drops 3x. acc[2][4]=32 AGPR, 8 waves,
// launch_bounds(512,2) (cap 128 >= ~85 arch + W-frags; <=64 caps spill: R4/11/13).
// STAGE 1: dst = padded 4-plane bf16 relu(conv+bias), ic' = col*4+nf -> 8B stores
// STAGE 2: dst = NCHW f32 resid+conv+bias (weights pre-permuted to match plane order)
template <int STAGE>
__global__ __launch_bounds__(512, 2) void k_hda_mfma(const u16* __restrict__ asrc,
    const u16* __restrict__ wall, const float* __restrict__ bias,
    const float* __restrict__ resid, void* __restrict__ dst) {
  __shared__ char lds[22528];  // 2 x 11264: A granules (pos*2+slot, bit3-xor swizzle)
  const int wg0 = blockIdx.x;
  const int wg = ((wg0 & 7) << 8) + (wg0 >> 3);
  const int b = wg >> 8;
  const int rr = wg & 255;
  const int by0 = (rr >> 4) << 4, bx0 = (rr & 15) << 4;
  const int tid = threadIdx.x, lane = tid & 63, wid = tid >> 6;  // wid 0..7
  const int col = lane & 15, kq = lane >> 4;
  const int hi = kq >> 1, sl2 = kq & 1;
  f32x4 acc[2][4];
#pragma unroll
  for (int i = 0; i < 2; ++i)
#pragma unroll
    for (int j = 0; j < 4; ++j) acc[i][j] = 0.f;
  hda_stage(asrc, lds, b, by0, bx0, 0, tid, wid);
#pragma unroll
  for (int cc = 0; cc < 4; ++cc) {
    __syncthreads();  // drains DMA for buf[cc&1]; prior reads of buf[(cc+1)&1] done
    if (cc < 3)
      hda_stage(asrc, lds + ((cc + 1) & 1) * 11264, b, by0, bx0, cc + 1, tid, wid);
    const char* lb = lds + (cc & 1) * 11264;
    const u16* wpc = wall + (size_t)b * 40960 + cc * 10240;
    __builtin_amdgcn_s_setprio(1);
#pragma unroll
    for (int s = 0; s < 5; ++s) {  // tap = 2s + hi  (tap 9 = zero pad)
      const int t0 = 2 * s, t1 = 2 * s + 1;
      const int d0 = (t0 / 3) * 18 + (t0 % 3);
      const int d1 = (t1 / 3) * 18 + (t1 % 3);
      const int dd = hi ? d1 : d0;
      bf16x8 a[2];
#pragma unroll
      for (int mf = 0; mf < 2; ++mf) {
        int pos = (wid * 2 + mf) * 18 + col + dd;
        int g = (pos * 2 + sl2) ^ ((pos >> 2) & 1);
        a[mf] = __builtin_bit_cast(bf16x8, *(const u16x8*)(lb + g * 16));
      }
      bf16x8 w[4];
#pragma unroll
      for (int nf = 0; nf < 4; ++nf)
        w[nf] = __builtin_bit_cast(bf16x8,
            *(const u16x8*)(wpc + (size_t)(nf * 16 + col) * 160 + s * 32 + kq * 8));
#pragma unroll
      for (int mf = 0; mf < 2; ++mf)
#pragma unroll
        for (int nf = 0; nf < 4; ++nf) acc[mf][nf] = mfma16(a[mf], w[nf], acc[mf][nf]);
    }
    __builtin_amdgcn_s_setprio(0);
  }
  const float* bb = bias + b * 64;
#pragma unroll
  for (int mf = 0; mf < 2; ++mf) {
    int y = by0 + wid * 2 + mf;
    if (STAGE == 1) {
#pragma unroll
      for (int r = 0; r < 4; ++r) {
        int x = bx0 + kq * 4 + r;
        u32x2 pk;
        pk[0] = (u32)f2bf(fmaxf(acc[mf][0][r] + bb[col], 0.f)) |
                ((u32)f2bf(fmaxf(acc[mf][1][r] + bb[16 + col], 0.f)) << 16);
        pk[1] = (u32)f2bf(fmaxf(acc[mf][2][r] + bb[32 + col], 0.f)) |
                ((u32)f2bf(fmaxf(acc[mf][3][r] + bb[48 + col], 0.f)) << 16);
        *(u32x2*)((u16*)dst + (size_t)(col >> 2) * PSP +
                  (((size_t)b * 258 + y + 1) * 258 + x + 1) * 16 + (col & 3) * 4) = pk;
      }
    } else {
#pragma unroll
      for (int nf = 0; nf < 4; ++nf) {
        int oc = nf * 16 + col;
        float bv = bb[oc];
        size_t o = (((size_t)b * 64 + oc) * 256 + y) * 256 + bx0 + kq * 4;
        f32x4 rx = *(const f32x4*)(resid + o);
        f32x4 vv;
#pragma unroll
        for (int r = 0; r < 4; ++r) vv[r] = rx[r] + acc[mf][nf][r] + bv;
        *(f32x4*)((float*)dst + o) = vv;
      }
    }
  }
}

extern "C" void kernel_launch(void* const* d_in, const int* in_sizes, int n_in,
                              void* d_out, int out_size, void* d_ws, size_t ws_size,
                              hipStream_t stream) {
  const float* x        = (const float*)d_in[0];
  const float* ow1      = (const float*)d_in[1];
  const float* ow2      = (const float*)d_in[2];
  const float* cw1      = (const float*)d_in[3];
  const float* cb1      = (const float*)d_in[4];
  const float* cw2      = (const float*)d_in[5];
  const float* cb2      = (const float*)d_in[6];
  const float* cw3      = (const float*)d_in[7];
  const float* cb3      = (const float*)d_in[8];
  const float* scale_w  = (const float*)d_in[9];
  const float* scale_b  = (const float*)d_in[10];
  const float* shift_w  = (const float*)d_in[11];
  const float* shift_b  = (const float*)d_in[12];
  const float* dyn1     = (const float*)d_in[13];
  const float* share1   = (const float*)d_in[14];
  const float* share1_b = (const float*)d_in[15];
  const float* dyn2     = (const float*)d_in[16];
  const float* share2   = (const float*)d_in[17];
  const float* share2_b = (const float*)d_in[18];
  float* out = (float*)d_out;

  char* p = (char*)d_ws;
  u16* xh   = (u16*)p;            p += PSP * 4 * 2;   // 4 padded planes
  u16* midh = (u16*)p;            p += PSP * 4 * 2;   // 4 padded planes
  u16* wbf1 = (u16*)p;            p += (size_t)327680 * 2;
  u16* wbf2 = (u16*)p;            p += (size_t)327680 * 2;
  u16* cwb1 = (u16*)p;            p += (size_t)106496 * 2;
  u16* cwb2 = (u16*)p;            p += (size_t)32 * 288 * 2;
  u16* cwb3 = (u16*)p;            p += (size_t)32 * 288 * 2;
  float* a_    = (float*)p;       p += 512 * 4;
  float* bias1 = (float*)p;       p += 512 * 4;
  float* bias2 = (float*)p;       p += 512 * 4;
  float* cond  = (float*)p;       p += 256 * 4;
  // cond-net temporaries overlap midh (dead before midh border-zero + hda1)
  u16* h1h = midh;                                   // 8*126*126*32 bf16 (permuted ch)
  u16* h2h = h1h + (size_t)8 * 126 * 126 * 32;       // 8*63*63*32 bf16
  float* h3 = (float*)(h2h + (size_t)8 * 63 * 63 * 32);  // 8*32*32*32 f32

  k_zero_border<<<129, 256, 0, stream>>>(xh);
  k_tr<<<dim3(8, 256, 8), 256, 0, stream>>>(x, xh);

  k_prep_cw1<<<(106496 + 255) / 256, 256, 0, stream>>>(cw1, cwb1);
  k_prep_cw<<<(32 * 288 + 255) / 256, 256, 0, stream>>>(cw2, cwb2, 32, 9, 32 * 288, 1);
  k_prep_cw<<<(32 * 288 + 255) / 256, 256, 0, stream>>>(cw3, cwb3, 32, 9, 32 * 288, 0);

  k_cond1_mfma<<<512, 256, 0, stream>>>(xh, cwb1, cb1, h1h);
  k_conv_s2<126, 63, 32, 3, 0><<<dim3(4, 8, 8), 256, 0, stream>>>(h1h, cwb2, cb2, h2h);
  k_conv_s2<63, 32, 32, 3, 1><<<dim3(2, 4, 8), 256, 0, stream>>>(h2h, cwb3, cb3, h3);

  k_mean<<<256, 256, 0, stream>>>(h3, cond);
  k_film<<<1, 512, 0, stream>>>(cond, scale_w, scale_b, shift_w, shift_b,
                                share1_b, share2_b, a_, bias1, bias2);

  k_zero_border<<<129, 256, 0, stream>>>(midh);

  k_prep_hda<<<(327680 + 255) / 256, 256, 0, stream>>>(dyn1, ow1, share1, a_, wbf1, 1, 0);
  k_prep_hda<<<(327680 + 255) / 256, 256, 0, stream>>>(dyn2, ow2, share2, a_, wbf2, 0, 1);

  k_hda_mfma<1><<<2048, 512, 0, stream>>>(xh, wbf1, bias1, nullptr, midh);
  k_hda_mfma<2><<<2048, 512, 0, stream>>>(midh, wbf2, bias2, x, out);
}

// Round 19
// 282.864 us; speedup vs baseline: 1.2162x; 1.2162x over previous
//
#include <hip/hip_runtime.h>

typedef unsigned short u16;
typedef unsigned int u32;
typedef __attribute__((ext_vector_type(8))) __bf16 bf16x8;
typedef __attribute__((ext_vector_type(8))) u16 u16x8;
typedef __attribute__((ext_vector_type(4))) float f32x4;
typedef __attribute__((ext_vector_type(2))) u32 u32x2;

// padded plane: [b][258][258][16ic]; 1-pixel zero border for DMA staging
static constexpr size_t PSP = (size_t)8 * 258 * 258 * 16;  // u16 elems per plane

#define GPTR(p) ((const __attribute__((address_space(1))) void*)(p))
#define LPTR(p) ((__attribute__((address_space(3))) void*)(p))

__device__ __forceinline__ u16 f2bf(float f) {
  u32 u = __builtin_bit_cast(u32, f);
  u = (u + 0x7FFFu + ((u >> 16) & 1u)) >> 16;
  return (u16)u;
}

__device__ __forceinline__ f32x4 mfma16(bf16x8 a, bf16x8 b, f32x4 c) {
  return __builtin_amdgcn_mfma_f32_16x16x32_bf16(a, b, c, 0, 0, 0);
}

// ---------- zero the 1-pixel border of a 4-plane padded array ----------
__global__ void k_zero_border(u16* __restrict__ base) {
  int idx = blockIdx.x * 256 + threadIdx.x;
  if (idx >= 4 * 8 * 1028) return;
  int p = idx / (8 * 1028), r = idx - p * (8 * 1028);
  int b = r / 1028, e = r - b * 1028;
  int y, x;
  if (e < 258) { y = 0; x = e; }
  else if (e < 516) { y = 257; x = e - 258; }
  else { int e2 = e - 516; y = 1 + (e2 >> 1); x = (e2 & 1) * 257; }
  u16* d = base + (size_t)p * PSP + (((size_t)b * 258 + y) * 258 + x) * 16;
  u16x8 z = (u16x8)0;
  *(u16x8*)d = z;
  *(u16x8*)(d + 8) = z;
}

// ---------- NCHW f32 -> 4-plane padded bf16: [p][b][1+y][1+x][16ic] ----------
__global__ __launch_bounds__(256) void k_tr(const float* __restrict__ x,
                                            u16* __restrict__ xh) {
  __shared__ float t[64][33];
  const int b = blockIdx.z, y = blockIdx.y, x0 = blockIdx.x * 32;
  const int tid = threadIdx.x;
  {
    int ic = tid >> 2, xo = (tid & 3) * 8;
    const float* s = x + (((size_t)b * 64 + ic) * 256 + y) * 256 + x0 + xo;
    f32x4 v0 = *(const f32x4*)s;
    f32x4 v1 = *(const f32x4*)(s + 4);
#pragma unroll
    for (int j = 0; j < 4; ++j) { t[ic][xo + j] = v0[j]; t[ic][xo + 4 + j] = v1[j]; }
  }
  __syncthreads();
  {
    int xc = tid & 31, slot = tid >> 5;  // slot 0..7 -> ic0 = slot*8
    int ic0 = slot * 8;
    u16x8 v;
#pragma unroll
    for (int j = 0; j < 8; ++j) v[j] = f2bf(t[ic0 + j][xc]);
    *(u16x8*)(xh + (size_t)(slot >> 1) * PSP +
              (((size_t)b * 258 + y + 1) * 258 + x0 + xc + 1) * 16 + (slot & 1) * 8) = v;
  }
}

// ---------- conv2/3 weights: [OC][IC][3][3] f32 -> [oc][tap*IC+icp] bf16 ----------
// perm=1: input channels arrive permuted as icp = (ic&15)*2 + (ic>>4)  (IC=32)
__global__ void k_prep_cw(const float* __restrict__ src, u16* __restrict__ dst,
                          int IC, int KK2, int n, int perm) {
  int d = blockIdx.x * 256 + threadIdx.x;
  if (d >= n) return;
  int per = KK2 * IC;
  int oc = d / per, r = d - oc * per;
  int tap = r / IC, icp = r - tap * IC;
  int ic = perm ? ((icp >> 1) + (icp & 1) * 16) : icp;
  dst[d] = f2bf(src[(oc * IC + ic) * KK2 + tap]);
}

// ---------- conv1 weights: [32][64][7][7] f32 -> [8 chunks][t(52)][oc(32)][8 ic] bf16 ----------
// t-major so DMA dests are linear; taps 49..51 zero-padded; chunk h = ic h*8..h*8+7
__global__ void k_prep_cw1(const float* __restrict__ src, u16* __restrict__ dst) {
  int d = blockIdx.x * 256 + threadIdx.x;  // 8*52*32*8 = 106496
  if (d >= 106496) return;
  int h = d / 13312, r = d - h * 13312;
  int t = r >> 8, r2 = r & 255;
  int oc = r2 >> 3, i = r2 & 7;
  float v = (t < 49) ? src[(oc * 64 + h * 8 + i) * 49 + t] : 0.f;
  dst[d] = f2bf(v);
}

// ---------- HDA weights -> [b][cc(4)][t(20)][oc(64)][j(8)] bf16 (t-major) ----------
// t = s*4+kq: tap = 2s + (kq>>1) (tap 9 zero-pad); ic-slot icp = cc*16 + (kq&1)*8 + j.
// perm=1 (stage 2): slot icp holds real channel ic = (icp&3)*16 + (icp>>2)
__global__ void k_prep_hda(const float* __restrict__ dyn, const float* __restrict__ ow,
                           const float* __restrict__ share, const float* __restrict__ a_,
                           u16* __restrict__ dst, int use_a, int perm) {
  int d = blockIdx.x * 256 + threadIdx.x;  // 8*4*20*64*8 = 327680
  if (d >= 327680) return;
  int b = d / 40960, r = d - b * 40960;
  int cc = r / 10240, r2 = r - cc * 10240;
  int t = r2 / 512, r3 = r2 - t * 512;
  int oc = r3 >> 3, j = r3 & 7;
  int s = t >> 2, kq = t & 3;
  int tap = 2 * s + (kq >> 1);
  float v = 0.f;
  if (tap < 9) {
    int icp = cc * 16 + (kq & 1) * 8 + j;
    int ic = perm ? ((icp & 3) * 16 + (icp >> 2)) : icp;
    v = (oc < 32) ? dyn[(oc * 64 + ic) * 9 + tap] * ow[((b * 32 + oc) * 64 + ic) * 9 + tap]
                  : share[((oc - 32) * 64 + ic) * 9 + tap];
    if (use_a) v *= a_[b * 64 + oc];
  }
  dst[d] = f2bf(v);
}

// ---------- cond conv1: 7x7 s2 p1 64->32, MFMA, DMA-staged A+W in LDS ----------
__global__ __launch_bounds__(256, 2) void k_cond1_mfma(const u16* __restrict__ xh,
    const u16* __restrict__ wp /*[8][52][32][8]*/, const float* __restrict__ cb,
    u16* __restrict__ dst) {
  __shared__ char lds[49152];  // [0,22528): A; [22528,49152): W
  const int wg0 = blockIdx.x;
  const int wg = ((wg0 & 7) << 6) | (wg0 >> 3);
  const int b = wg >> 6, rr = wg & 63;
  const int oh0 = (rr >> 3) << 4, ow0 = (rr & 7) << 4;
  const int tid = threadIdx.x, lane = tid & 63, wid = tid >> 6;
  const int col = lane & 15, kq = lane >> 4;
  f32x4 acc[4][2];
#pragma unroll
  for (int i = 0; i < 4; ++i)
#pragma unroll
    for (int j = 0; j < 2; ++j) acc[i][j] = 0.f;
  int pb[4];
#pragma unroll
  for (int mf = 0; mf < 4; ++mf) pb[mf] = (2 * (wid * 4 + mf)) * 37 + 2 * col;
#pragma unroll 1
  for (int h = 0; h < 8; ++h) {
    __syncthreads();
    // A DMA: granule g holds A[swz(g)]; source pre-swizzled, dest linear
#pragma unroll
    for (int it = 0; it < 6; ++it) {
      if (it < 5 || wid < 2) {
        int g = it * 256 + tid;
        int i = g ^ ((g >> 3) & 7);
        if (i >= 1406) i = 0;  // dummy granules (never read)
        int r = i / 37, cc2 = i - r * 37;
        const u16* src = xh + (size_t)(h >> 1) * PSP +
            (((size_t)b * 258 + 2 * oh0 + r) * 258 + 2 * ow0 + cc2) * 16 + (h & 1) * 8;
        __builtin_amdgcn_global_load_lds(GPTR(src),
            LPTR(lds + (it * 256 + wid * 64) * 16), 16, 0, 0);
      }
    }
    // W DMA: [t(52)][oc(32)] linear dest
#pragma unroll
    for (int it = 0; it < 7; ++it) {
      if (it < 6 || wid < 2) {
        int g = it * 256 + tid;
        int t = g >> 5, oc = g & 31;
        const u16* src = wp + h * 13312 + t * 256 + oc * 8;
        __builtin_amdgcn_global_load_lds(GPTR(src),
            LPTR(lds + 22528 + (it * 256 + wid * 64) * 16), 16, 0, 0);
      }
    }
    __syncthreads();
    __builtin_amdgcn_s_setprio(1);
#pragma unroll
    for (int s = 0; s < 13; ++s) {  // taps 4s+kq
      const int t0 = 4 * s;
      const int kh0 = t0 / 7, r7 = t0 % 7;
      int carry = (kq >= 7 - r7) ? 1 : 0;
      int kh = kh0 + carry;
      int kw = r7 + kq - carry * 7;
      int prow = kh * 37 + kw;
      bf16x8 a[4];
#pragma unroll
      for (int mf = 0; mf < 4; ++mf) {
        int pos = pb[mf] + prow;
        int g = pos ^ ((pos >> 3) & 7);
        a[mf] = __builtin_bit_cast(bf16x8, *(const u16x8*)(lds + g * 16));
      }
      bf16x8 w[2];
#pragma unroll
      for (int nf = 0; nf < 2; ++nf)
        w[nf] = __builtin_bit_cast(bf16x8,
            *(const u16x8*)(lds + 22528 + (((4 * s + kq) * 32) + nf * 16 + col) * 16));
#pragma unroll
      for (int mf = 0; mf < 4; ++mf)
#pragma unroll
        for (int nf = 0; nf < 2; ++nf) acc[mf][nf] = mfma16(a[mf], w[nf], acc[mf][nf]);
    }
    __builtin_amdgcn_s_setprio(0);
  }
  const float bv0 = cb[col], bv1 = cb[16 + col];
#pragma unroll
  for (int mf = 0; mf < 4; ++mf) {
    int oh = oh0 + wid * 4 + mf;
    if (oh >= 126) continue;
#pragma unroll
    for (int r = 0; r < 4; ++r) {
      int ow = ow0 + kq * 4 + r;
      if (ow >= 126) continue;
      u32 pack = (u32)f2bf(fmaxf(acc[mf][0][r] + bv0, 0.f)) |
                 ((u32)f2bf(fmaxf(acc[mf][1][r] + bv1, 0.f)) << 16);
      *(u32*)(dst + (((size_t)b * 126 + oh) * 126 + ow) * 32 + col * 2) = pack;
    }
  }
}

// ---------- generic stride-2 pad-1 conv (small conv2/conv3) ----------
template <int HI, int HO, int IC, int KK, int OUTF32>
__global__ __launch_bounds__(256, 4) void k_conv_s2(const u16* __restrict__ src,
    const u16* __restrict__ wgt, const float* __restrict__ bias, void* __restrict__ dst) {
  const int b = blockIdx.z;
  const int by0 = blockIdx.y * 8, bx0 = blockIdx.x * 16;
  const int tid = threadIdx.x, lane = tid & 63, wid = tid >> 6;
  const int col = lane & 15, kq = lane >> 4;
  f32x4 acc[2][2];
#pragma unroll
  for (int i = 0; i < 2; ++i)
#pragma unroll
    for (int j = 0; j < 2; ++j) acc[i][j] = 0.f;
  const u16x8 Z = (u16x8)0;
#pragma unroll
  for (int kh = 0; kh < KK; ++kh) {
#pragma unroll
    for (int kw = 0; kw < KK; ++kw) {
#pragma unroll
      for (int h = 0; h < IC / 32; ++h) {
        bf16x8 a[2];
#pragma unroll
        for (int mf = 0; mf < 2; ++mf) {
          int oh = by0 + wid * 2 + mf;
          int ih = 2 * oh - 1 + kh;
          int ix = 2 * (bx0 + col) - 1 + kw;
          int ic = h * 32 + kq * 8;
          u16x8 raw = Z;
          if ((unsigned)ih < (unsigned)HI && (unsigned)ix < (unsigned)HI)
            raw = *(const u16x8*)(src + (((size_t)b * HI + ih) * HI + ix) * IC + ic);
          a[mf] = __builtin_bit_cast(bf16x8, raw);
        }
        int k0 = (kh * KK + kw) * IC + h * 32 + kq * 8;
        bf16x8 w[2];
#pragma unroll
        for (int nf = 0; nf < 2; ++nf)
          w[nf] = __builtin_bit_cast(bf16x8,
                    *(const u16x8*)(wgt + (size_t)(nf * 16 + col) * (KK * KK * IC) + k0));
#pragma unroll
        for (int mf = 0; mf < 2; ++mf)
#pragma unroll
          for (int nf = 0; nf < 2; ++nf) acc[mf][nf] = mfma16(a[mf], w[nf], acc[mf][nf]);
      }
    }
  }
#pragma unroll
  for (int mf = 0; mf < 2; ++mf) {
    int oh = by0 + wid * 2 + mf;
    if (oh >= HO) continue;
#pragma unroll
    for (int nf = 0; nf < 2; ++nf) {
      int oc = nf * 16 + col;
      float bv = bias[oc];
#pragma unroll
      for (int r = 0; r < 4; ++r) {
        int ow = bx0 + kq * 4 + r;
        if (ow >= HO) continue;
        float v = fmaxf(acc[mf][nf][r] + bv, 0.f);
        if (OUTF32)
          ((float*)dst)[(((size_t)b * 32 + oc) * HO + oh) * HO + ow] = v;
        else
          ((u16*)dst)[(((size_t)b * HO + oh) * HO + ow) * 32 + oc] = f2bf(v);
      }
    }
  }
}

// ---------- mean over 32x32 -> cond[8*32] ----------
__global__ void k_mean(const float* __restrict__ h3, float* __restrict__ cond) {
  int bo = blockIdx.x;
  int tid = threadIdx.x;
  float s = 0.f;
  for (int i = tid; i < 1024; i += 256) s += h3[bo * 1024 + i];
  __shared__ float red[256];
  red[tid] = s;
  __syncthreads();
  for (int o = 128; o > 0; o >>= 1) {
    if (tid < o) red[tid] += red[tid + o];
    __syncthreads();
  }
  if (tid == 0) cond[bo] = red[0] * (1.f / 1024.f);
}

// ---------- FiLM fold ----------
__global__ void k_film(const float* __restrict__ cond,
                       const float* __restrict__ scale_w, const float* __restrict__ scale_b,
                       const float* __restrict__ shift_w, const float* __restrict__ shift_b,
                       const float* __restrict__ share1_b, const float* __restrict__ share2_b,
                       float* __restrict__ a_, float* __restrict__ bias1,
                       float* __restrict__ bias2) {
  int t = threadIdx.x;  // 512
  int b = t >> 6, j = t & 63;
  float s = scale_b[j], sh = shift_b[j];
  for (int k = 0; k < 32; ++k) {
    float c = cond[b * 32 + k];
    s = fmaf(c, scale_w[j * 32 + k], s);
    sh = fmaf(c, shift_w[j * 32 + k], sh);
  }
  float a = s + 1.f;
  float b0 = (j < 32) ? 0.f : share1_b[j - 32];
  a_[t] = a;
  bias1[t] = fmaf(a, b0, sh);
  bias2[t] = (j < 32) ? 0.f : share2_b[j - 32];
}

// ---------- HDA chunk stage (256 threads): A 1224 gran + W 1280 gran ----------
// buffer: [0,19584) A (34x18 pos x 2 slots, swizzled); [19584,40064) W [t(20)][oc(64)]
__device__ __forceinline__ void hda_stage(const u16* __restrict__ asrc,
                                          const u16* __restrict__ wall,
                                          char* lb, int b, int by0, int bx0,
                                          int cc, int tid) {
  const u16* ap = asrc + (size_t)cc * PSP;
  const u16* wp = wall + (size_t)b * 40960 + cc * 10240;
  // A: content[g] = A[g ^ bit3(g)] (involution within pairs), dest linear
#pragma unroll
  for (int it = 0; it < 5; ++it) {
    if (it < 4 || tid < 200) {
      int g = it * 256 + tid;
      int i = g ^ ((g >> 3) & 1);
      int pos = i >> 1, sl = i & 1;
      if (pos >= 612) { pos = 0; sl = 0; }
      int yy = pos / 18, xx = pos - yy * 18;
      const u16* src = ap + (((size_t)b * 258 + by0 + yy) * 258 + bx0 + xx) * 16 + sl * 8;
      __builtin_amdgcn_global_load_lds(GPTR(src), LPTR(lb + g * 16), 16, 0, 0);
    }
  }
  // W: 1280 granules = 5*256 exactly; src/dst both linear (t-major prep)
#pragma unroll
  for (int it = 0; it < 5; ++it) {
    int g = it * 256 + tid;
    __builtin_amdgcn_global_load_lds(GPTR(wp + g * 8), LPTR(lb + 19584 + g * 16), 16, 0, 0);
  }
}

// ---------- HDA conv 3x3 s1 p1 64->64, MFMA ----------
// LDS-throughput fix: wave = 8 rows x 64 oc (acc[8][4] = 128 AGPR, 256-reg class,
// 2 waves/SIMD) -> 12 LDS reads per 32 MFMA (was 6 per 8). Block = 4 waves = 32x16 px.
// Double-buffered A+W (80128B LDS -> 2 blocks/CU), DMA staging, setprio.
// launch_bounds(256,2): cap 256 >= ~210 (NOT the 128 cap - R12 evidence).
// STAGE 1: dst = padded 4-plane bf16 relu(conv+bias), ic' = col*4+nf -> 8B stores
// STAGE 2: dst = NCHW f32 resid+conv+bias (weights pre-permuted to match plane order)
template <int STAGE>
__global__ __launch_bounds__(256, 2) void k_hda_mfma(const u16* __restrict__ asrc,
    const u16* __restrict__ wall, const float* __restrict__ bias,
    const float* __restrict__ resid, void* __restrict__ dst) {
  __shared__ char lds[80128];  // 2 x 40064
  const int wg0 = blockIdx.x;  // 1024 = 8 XCD x 128 (bijective swizzle)
  const int wg = ((wg0 & 7) << 7) | (wg0 >> 3);
  const int b = wg >> 7;
  const int rr = wg & 127;
  const int by0 = (rr >> 4) * 32, bx0 = (rr & 15) * 16;
  const int tid = threadIdx.x, lane = tid & 63, wid = tid >> 6;  // wid 0..3
  const int col = lane & 15, kq = lane >> 4;
  const int hi = kq >> 1, sl2 = kq & 1;
  f32x4 acc[8][4];
#pragma unroll
  for (int i = 0; i < 8; ++i)
#pragma unroll
    for (int j = 0; j < 4; ++j) acc[i][j] = 0.f;
  hda_stage(asrc, wall, lds, b, by0, bx0, 0, tid);
#pragma unroll
  for (int cc = 0; cc < 4; ++cc) {
    __syncthreads();  // drains DMA for buf[cc&1]; prior reads of buf[(cc+1)&1] done
    if (cc < 3)
      hda_stage(asrc, wall, lds + ((cc + 1) & 1) * 40064, b, by0, bx0, cc + 1, tid);
    const char* lb = lds + (cc & 1) * 40064;
    __builtin_amdgcn_s_setprio(1);
#pragma unroll
    for (int s = 0; s < 5; ++s) {  // tap = 2s + hi  (tap 9 = zero pad)
      const int t0 = 2 * s, t1 = 2 * s + 1;
      const int d0 = (t0 / 3) * 18 + (t0 % 3);
      const int d1 = (t1 / 3) * 18 + (t1 % 3);
      const int dd = hi ? d1 : d0;
      bf16x8 a[8];
#pragma unroll
      for (int mf = 0; mf < 8; ++mf) {
        int pos = (wid * 8 + mf) * 18 + col + dd;
        int g = (pos * 2 + sl2) ^ ((pos >> 2) & 1);
        a[mf] = __builtin_bit_cast(bf16x8, *(const u16x8*)(lb + g * 16));
      }
      bf16x8 w[4];
#pragma unroll
      for (int nf = 0; nf < 4; ++nf)
        w[nf] = __builtin_bit_cast(bf16x8,
            *(const u16x8*)(lb + 19584 + ((s * 4 + kq) * 64 + nf * 16 + col) * 16));
#pragma unroll
      for (int mf = 0; mf < 8; ++mf)
#pragma unroll
        for (int nf = 0; nf < 4; ++nf) acc[mf][nf] = mfma16(a[mf], w[nf], acc[mf][nf]);
    }
    __builtin_amdgcn_s_setprio(0);
  }
  const float* bb = bias + b * 64;
#pragma unroll
  for (int mf = 0; mf < 8; ++mf) {
    int y = by0 + wid * 8 + mf;
    if (STAGE == 1) {
#pragma unroll
      for (int r = 0; r < 4; ++r) {
        int x = bx0 + kq * 4 + r;
        u32x2 pk;
        pk[0] = (u32)f2bf(fmaxf(acc[mf][0][r] + bb[col], 0.f)) |
                ((u32)f2bf(fmaxf(acc[mf][1][r] + bb[16 + col], 0.f)) << 16);
        pk[1] = (u32)f2bf(fmaxf(acc[mf][2][r] + bb[32 + col], 0.f)) |
                ((u32)f2bf(fmaxf(acc[mf][3][r] + bb[48 + col], 0.f)) << 16);
        *(u32x2*)((u16*)dst + (size_t)(col >> 2) * PSP +
                  (((size_t)b * 258 + y + 1) * 258 + x + 1) * 16 + (col & 3) * 4) = pk;
      }
    } else {
#pragma unroll
      for (int nf = 0; nf < 4; ++nf) {
        int oc = nf * 16 + col;
        float bv = bb[oc];
        size_t o = (((size_t)b * 64 + oc) * 256 + y) * 256 + bx0 + kq * 4;
        f32x4 rx = *(const f32x4*)(resid + o);
        f32x4 vv;
#pragma unroll
        for (int r = 0; r < 4; ++r) vv[r] = rx[r] + acc[mf][nf][r] + bv;
        *(f32x4*)((float*)dst + o) = vv;
      }
    }
  }
}

extern "C" void kernel_launch(void* const* d_in, const int* in_sizes, int n_in,
                              void* d_out, int out_size, void* d_ws, size_t ws_size,
                              hipStream_t stream) {
  const float* x        = (const float*)d_in[0];
  const float* ow1      = (const float*)d_in[1];
  const float* ow2      = (const float*)d_in[2];
  const float* cw1      = (const float*)d_in[3];
  const float* cb1      = (const float*)d_in[4];
  const float* cw2      = (const float*)d_in[5];
  const float* cb2      = (const float*)d_in[6];
  const float* cw3      = (const float*)d_in[7];
  const float* cb3      = (const float*)d_in[8];
  const float* scale_w  = (const float*)d_in[9];
  const float* scale_b  = (const float*)d_in[10];
  const float* shift_w  = (const float*)d_in[11];
  const float* shift_b  = (const float*)d_in[12];
  const float* dyn1     = (const float*)d_in[13];
  const float* share1   = (const float*)d_in[14];
  const float* share1_b = (const float*)d_in[15];
  const float* dyn2     = (const float*)d_in[16];
  const float* share2   = (const float*)d_in[17];
  const float* share2_b = (const float*)d_in[18];
  float* out = (float*)d_out;

  char* p = (char*)d_ws;
  u16* xh   = (u16*)p;            p += PSP * 4 * 2;   // 4 padded planes
  u16* midh = (u16*)p;            p += PSP * 4 * 2;   // 4 padded planes
  u16* wbf1 = (u16*)p;            p += (size_t)327680 * 2;
  u16* wbf2 = (u16*)p;            p += (size_t)327680 * 2;
  u16* cwb1 = (u16*)p;            p += (size_t)106496 * 2;
  u16* cwb2 = (u16*)p;            p += (size_t)32 * 288 * 2;
  u16* cwb3 = (u16*)p;            p += (size_t)32 * 288 * 2;
  float* a_    = (float*)p;       p += 512 * 4;
  float* bias1 = (float*)p;       p += 512 * 4;
  float* bias2 = (float*)p;       p += 512 * 4;
  float* cond  = (float*)p;       p += 256 * 4;
  // cond-net temporaries overlap midh (dead before midh border-zero + hda1)
  u16* h1h = midh;                                   // 8*126*126*32 bf16 (permuted ch)
  u16* h2h = h1h + (size_t)8 * 126 * 126 * 32;       // 8*63*63*32 bf16
  float* h3 = (float*)(h2h + (size_t)8 * 63 * 63 * 32);  // 8*32*32*32 f32

  k_zero_border<<<129, 256, 0, stream>>>(xh);
  k_tr<<<dim3(8, 256, 8), 256, 0, stream>>>(x, xh);

  k_prep_cw1<<<(106496 + 255) / 256, 256, 0, stream>>>(cw1, cwb1);
  k_prep_cw<<<(32 * 288 + 255) / 256, 256, 0, stream>>>(cw2, cwb2, 32, 9, 32 * 288, 1);
  k_prep_cw<<<(32 * 288 + 255) / 256, 256, 0, stream>>>(cw3, cwb3, 32, 9, 32 * 288, 0);

  k_cond1_mfma<<<512, 256, 0, stream>>>(xh, cwb1, cb1, h1h);
  k_conv_s2<126, 63, 32, 3, 0><<<dim3(4, 8, 8), 256, 0, stream>>>(h1h, cwb2, cb2, h2h);
  k_conv_s2<63, 32, 32, 3, 1><<<dim3(2, 4, 8), 256, 0, stream>>>(h2h, cwb3, cb3, h3);

  k_mean<<<256, 256, 0, stream>>>(h3, cond);
  k_film<<<1, 512, 0, stream>>>(cond, scale_w, scale_b, shift_w, shift_b,
                                share1_b, share2_b, a_, bias1, bias2);

  k_zero_border<<<129, 256, 0, stream>>>(midh);

  k_prep_hda<<<(327680 + 255) / 256, 256, 0, stream>>>(dyn1, ow1, share1, a_, wbf1, 1, 0);
  k_prep_hda<<<(327680 + 255) / 256, 256, 0, stream>>>(dyn2, ow2, share2, a_, wbf2, 0, 1);

  k_hda_mfma<1><<<1024, 256, 0, stream>>>(xh, wbf1, bias1, nullptr, midh);
  k_hda_mfma<2><<<1024, 256, 0, stream>>>(midh, wbf2, bias2, x, out);
}

// Round 20
// 249.283 us; speedup vs baseline: 1.3801x; 1.1347x over previous
//
#include <hip/hip_runtime.h>

typedef unsigned short u16;
typedef unsigned int u32;
typedef __attribute__((ext_vector_type(8))) __bf16 bf16x8;
typedef __attribute__((ext_vector_type(8))) u16 u16x8;
typedef __attribute__((ext_vector_type(4))) float f32x4;
typedef __attribute__((ext_vector_type(2))) u32 u32x2;

// padded plane: [b][258][258][16ic]; 1-pixel zero border for DMA staging
static constexpr size_t PSP = (size_t)8 * 258 * 258 * 16;  // u16 elems per plane

#define GPTR(p) ((const __attribute__((address_space(1))) void*)(p))
#define LPTR(p) ((__attribute__((address_space(3))) void*)(p))

__device__ __forceinline__ u16 f2bf(float f) {
  u32 u = __builtin_bit_cast(u32, f);
  u = (u + 0x7FFFu + ((u >> 16) & 1u)) >> 16;
  return (u16)u;
}

__device__ __forceinline__ f32x4 mfma16(bf16x8 a, bf16x8 b, f32x4 c) {
  return __builtin_amdgcn_mfma_f32_16x16x32_bf16(a, b, c, 0, 0, 0);
}

// ---------- zero the 1-pixel border of a 4-plane padded array ----------
__global__ void k_zero_border(u16* __restrict__ base) {
  int idx = blockIdx.x * 256 + threadIdx.x;
  if (idx >= 4 * 8 * 1028) return;
  int p = idx / (8 * 1028), r = idx - p * (8 * 1028);
  int b = r / 1028, e = r - b * 1028;
  int y, x;
  if (e < 258) { y = 0; x = e; }
  else if (e < 516) { y = 257; x = e - 258; }
  else { int e2 = e - 516; y = 1 + (e2 >> 1); x = (e2 & 1) * 257; }
  u16* d = base + (size_t)p * PSP + (((size_t)b * 258 + y) * 258 + x) * 16;
  u16x8 z = (u16x8)0;
  *(u16x8*)d = z;
  *(u16x8*)(d + 8) = z;
}

// ---------- NCHW f32 -> 4-plane padded bf16: [p][b][1+y][1+x][16ic] ----------
__global__ __launch_bounds__(256) void k_tr(const float* __restrict__ x,
                                            u16* __restrict__ xh) {
  __shared__ float t[64][33];
  const int b = blockIdx.z, y = blockIdx.y, x0 = blockIdx.x * 32;
  const int tid = threadIdx.x;
  {
    int ic = tid >> 2, xo = (tid & 3) * 8;
    const float* s = x + (((size_t)b * 64 + ic) * 256 + y) * 256 + x0 + xo;
    f32x4 v0 = *(const f32x4*)s;
    f32x4 v1 = *(const f32x4*)(s + 4);
#pragma unroll
    for (int j = 0; j < 4; ++j) { t[ic][xo + j] = v0[j]; t[ic][xo + 4 + j] = v1[j]; }
  }
  __syncthreads();
  {
    int xc = tid & 31, slot = tid >> 5;  // slot 0..7 -> ic0 = slot*8
    int ic0 = slot * 8;
    u16x8 v;
#pragma unroll
    for (int j = 0; j < 8; ++j) v[j] = f2bf(t[ic0 + j][xc]);
    *(u16x8*)(xh + (size_t)(slot >> 1) * PSP +
              (((size_t)b * 258 + y + 1) * 258 + x0 + xc + 1) * 16 + (slot & 1) * 8) = v;
  }
}

// ---------- conv2/3 weights: [OC][IC][3][3] f32 -> [oc][tap*IC+icp] bf16 ----------
// perm=1: input channels arrive permuted as icp = (ic&15)*2 + (ic>>4)  (IC=32)
__global__ void k_prep_cw(const float* __restrict__ src, u16* __restrict__ dst,
                          int IC, int KK2, int n, int perm) {
  int d = blockIdx.x * 256 + threadIdx.x;
  if (d >= n) return;
  int per = KK2 * IC;
  int oc = d / per, r = d - oc * per;
  int tap = r / IC, icp = r - tap * IC;
  int ic = perm ? ((icp >> 1) + (icp & 1) * 16) : icp;
  dst[d] = f2bf(src[(oc * IC + ic) * KK2 + tap]);
}

// ---------- conv1 weights: [32][64][7][7] f32 -> [8 chunks][t(52)][oc(32)][8 ic] bf16 ----------
// t-major so DMA dests are linear; taps 49..51 zero-padded; chunk h = ic h*8..h*8+7
__global__ void k_prep_cw1(const float* __restrict__ src, u16* __restrict__ dst) {
  int d = blockIdx.x * 256 + threadIdx.x;  // 8*52*32*8 = 106496
  if (d >= 106496) return;
  int h = d / 13312, r = d - h * 13312;
  int t = r >> 8, r2 = r & 255;
  int oc = r2 >> 3, i = r2 & 7;
  float v = (t < 49) ? src[(oc * 64 + h * 8 + i) * 49 + t] : 0.f;
  dst[d] = f2bf(v);
}

// ---------- HDA weights -> [b][cc(4)][t(20)][oc(64)][j(8)] bf16 (t-major, conflict-free) ----------
// t = s*4+kq: tap = 2s + (kq>>1) (tap 9 zero-pad); ic-slot icp = cc*16 + (kq&1)*8 + j.
// perm=1 (stage 2): slot icp holds real channel ic = (icp&3)*16 + (icp>>2)
__global__ void k_prep_hda(const float* __restrict__ dyn, const float* __restrict__ ow,
                           const float* __restrict__ share, const float* __restrict__ a_,
                           u16* __restrict__ dst, int use_a, int perm) {
  int d = blockIdx.x * 256 + threadIdx.x;  // 8*4*20*64*8 = 327680
  if (d >= 327680) return;
  int b = d / 40960, r = d - b * 40960;
  int cc = r / 10240, r2 = r - cc * 10240;
  int t = r2 / 512, r3 = r2 - t * 512;
  int oc = r3 >> 3, j = r3 & 7;
  int s = t >> 2, kq = t & 3;
  int tap = 2 * s + (kq >> 1);
  float v = 0.f;
  if (tap < 9) {
    int icp = cc * 16 + (kq & 1) * 8 + j;
    int ic = perm ? ((icp & 3) * 16 + (icp >> 2)) : icp;
    v = (oc < 32) ? dyn[(oc * 64 + ic) * 9 + tap] * ow[((b * 32 + oc) * 64 + ic) * 9 + tap]
                  : share[((oc - 32) * 64 + ic) * 9 + tap];
    if (use_a) v *= a_[b * 64 + oc];
  }
  dst[d] = f2bf(v);
}

// ---------- cond conv1: 7x7 s2 p1 64->32, MFMA, DMA-staged A+W in LDS ----------
__global__ __launch_bounds__(256, 2) void k_cond1_mfma(const u16* __restrict__ xh,
    const u16* __restrict__ wp /*[8][52][32][8]*/, const float* __restrict__ cb,
    u16* __restrict__ dst) {
  __shared__ char lds[49152];  // [0,22528): A; [22528,49152): W
  const int wg0 = blockIdx.x;
  const int wg = ((wg0 & 7) << 6) | (wg0 >> 3);
  const int b = wg >> 6, rr = wg & 63;
  const int oh0 = (rr >> 3) << 4, ow0 = (rr & 7) << 4;
  const int tid = threadIdx.x, lane = tid & 63, wid = tid >> 6;
  const int col = lane & 15, kq = lane >> 4;
  f32x4 acc[4][2];
#pragma unroll
  for (int i = 0; i < 4; ++i)
#pragma unroll
    for (int j = 0; j < 2; ++j) acc[i][j] = 0.f;
  int pb[4];
#pragma unroll
  for (int mf = 0; mf < 4; ++mf) pb[mf] = (2 * (wid * 4 + mf)) * 37 + 2 * col;
#pragma unroll 1
  for (int h = 0; h < 8; ++h) {
    __syncthreads();
    // A DMA: granule g holds A[swz(g)]; source pre-swizzled, dest linear
#pragma unroll
    for (int it = 0; it < 6; ++it) {
      if (it < 5 || wid < 2) {
        int g = it * 256 + tid;
        int i = g ^ ((g >> 3) & 7);
        if (i >= 1406) i = 0;  // dummy granules (never read)
        int r = i / 37, cc2 = i - r * 37;
        const u16* src = xh + (size_t)(h >> 1) * PSP +
            (((size_t)b * 258 + 2 * oh0 + r) * 258 + 2 * ow0 + cc2) * 16 + (h & 1) * 8;
        __builtin_amdgcn_global_load_lds(GPTR(src),
            LPTR(lds + (it * 256 + wid * 64) * 16), 16, 0, 0);
      }
    }
    // W DMA: [t(52)][oc(32)] linear dest
#pragma unroll
    for (int it = 0; it < 7; ++it) {
      if (it < 6 || wid < 2) {
        int g = it * 256 + tid;
        int t = g >> 5, oc = g & 31;
        const u16* src = wp + h * 13312 + t * 256 + oc * 8;
        __builtin_amdgcn_global_load_lds(GPTR(src),
            LPTR(lds + 22528 + (it * 256 + wid * 64) * 16), 16, 0, 0);
      }
    }
    __syncthreads();
    __builtin_amdgcn_s_setprio(1);
#pragma unroll
    for (int s = 0; s < 13; ++s) {  // taps 4s+kq
      const int t0 = 4 * s;
      const int kh0 = t0 / 7, r7 = t0 % 7;
      int carry = (kq >= 7 - r7) ? 1 : 0;
      int kh = kh0 + carry;
      int kw = r7 + kq - carry * 7;
      int prow = kh * 37 + kw;
      bf16x8 a[4];
#pragma unroll
      for (int mf = 0; mf < 4; ++mf) {
        int pos = pb[mf] + prow;
        int g = pos ^ ((pos >> 3) & 7);
        a[mf] = __builtin_bit_cast(bf16x8, *(const u16x8*)(lds + g * 16));
      }
      bf16x8 w[2];
#pragma unroll
      for (int nf = 0; nf < 2; ++nf)
        w[nf] = __builtin_bit_cast(bf16x8,
            *(const u16x8*)(lds + 22528 + (((4 * s + kq) * 32) + nf * 16 + col) * 16));
#pragma unroll
      for (int mf = 0; mf < 4; ++mf)
#pragma unroll
        for (int nf = 0; nf < 2; ++nf) acc[mf][nf] = mfma16(a[mf], w[nf], acc[mf][nf]);
    }
    __builtin_amdgcn_s_setprio(0);
  }
  const float bv0 = cb[col], bv1 = cb[16 + col];
#pragma unroll
  for (int mf = 0; mf < 4; ++mf) {
    int oh = oh0 + wid * 4 + mf;
    if (oh >= 126) continue;
#pragma unroll
    for (int r = 0; r < 4; ++r) {
      int ow = ow0 + kq * 4 + r;
      if (ow >= 126) continue;
      u32 pack = (u32)f2bf(fmaxf(acc[mf][0][r] + bv0, 0.f)) |
                 ((u32)f2bf(fmaxf(acc[mf][1][r] + bv1, 0.f)) << 16);
      *(u32*)(dst + (((size_t)b * 126 + oh) * 126 + ow) * 32 + col * 2) = pack;
    }
  }
}

// ---------- generic stride-2 pad-1 conv (small conv2/conv3) ----------
template <int HI, int HO, int IC, int KK, int OUTF32>
__global__ __launch_bounds__(256, 4) void k_conv_s2(const u16* __restrict__ src,
    const u16* __restrict__ wgt, const float* __restrict__ bias, void* __restrict__ dst) {
  const int b = blockIdx.z;
  const int by0 = blockIdx.y * 8, bx0 = blockIdx.x * 16;
  const int tid = threadIdx.x, lane = tid & 63, wid = tid >> 6;
  const int col = lane & 15, kq = lane >> 4;
  f32x4 acc[2][2];
#pragma unroll
  for (int i = 0; i < 2; ++i)
#pragma unroll
    for (int j = 0; j < 2; ++j) acc[i][j] = 0.f;
  const u16x8 Z = (u16x8)0;
#pragma unroll
  for (int kh = 0; kh < KK; ++kh) {
#pragma unroll
    for (int kw = 0; kw < KK; ++kw) {
#pragma unroll
      for (int h = 0; h < IC / 32; ++h) {
        bf16x8 a[2];
#pragma unroll
        for (int mf = 0; mf < 2; ++mf) {
          int oh = by0 + wid * 2 + mf;
          int ih = 2 * oh - 1 + kh;
          int ix = 2 * (bx0 + col) - 1 + kw;
          int ic = h * 32 + kq * 8;
          u16x8 raw = Z;
          if ((unsigned)ih < (unsigned)HI && (unsigned)ix < (unsigned)HI)
            raw = *(const u16x8*)(src + (((size_t)b * HI + ih) * HI + ix) * IC + ic);
          a[mf] = __builtin_bit_cast(bf16x8, raw);
        }
        int k0 = (kh * KK + kw) * IC + h * 32 + kq * 8;
        bf16x8 w[2];
#pragma unroll
        for (int nf = 0; nf < 2; ++nf)
          w[nf] = __builtin_bit_cast(bf16x8,
                    *(const u16x8*)(wgt + (size_t)(nf * 16 + col) * (KK * KK * IC) + k0));
#pragma unroll
        for (int mf = 0; mf < 2; ++mf)
#pragma unroll
          for (int nf = 0; nf < 2; ++nf) acc[mf][nf] = mfma16(a[mf], w[nf], acc[mf][nf]);
      }
    }
  }
#pragma unroll
  for (int mf = 0; mf < 2; ++mf) {
    int oh = by0 + wid * 2 + mf;
    if (oh >= HO) continue;
#pragma unroll
    for (int nf = 0; nf < 2; ++nf) {
      int oc = nf * 16 + col;
      float bv = bias[oc];
#pragma unroll
      for (int r = 0; r < 4; ++r) {
        int ow = bx0 + kq * 4 + r;
        if (ow >= HO) continue;
        float v = fmaxf(acc[mf][nf][r] + bv, 0.f);
        if (OUTF32)
          ((float*)dst)[(((size_t)b * 32 + oc) * HO + oh) * HO + ow] = v;
        else
          ((u16*)dst)[(((size_t)b * HO + oh) * HO + ow) * 32 + oc] = f2bf(v);
      }
    }
  }
}

// ---------- mean over 32x32 -> cond[8*32] ----------
__global__ void k_mean(const float* __restrict__ h3, float* __restrict__ cond) {
  int bo = blockIdx.x;
  int tid = threadIdx.x;
  float s = 0.f;
  for (int i = tid; i < 1024; i += 256) s += h3[bo * 1024 + i];
  __shared__ float red[256];
  red[tid] = s;
  __syncthreads();
  for (int o = 128; o > 0; o >>= 1) {
    if (tid < o) red[tid] += red[tid + o];
    __syncthreads();
  }
  if (tid == 0) cond[bo] = red[0] * (1.f / 1024.f);
}

// ---------- FiLM fold ----------
__global__ void k_film(const float* __restrict__ cond,
                       const float* __restrict__ scale_w, const float* __restrict__ scale_b,
                       const float* __restrict__ shift_w, const float* __restrict__ shift_b,
                       const float* __restrict__ share1_b, const float* __restrict__ share2_b,
                       float* __restrict__ a_, float* __restrict__ bias1,
                       float* __restrict__ bias2) {
  int t = threadIdx.x;  // 512
  int b = t >> 6, j = t & 63;
  float s = scale_b[j], sh = shift_b[j];
  for (int k = 0; k < 32; ++k) {
    float c = cond[b * 32 + k];
    s = fmaf(c, scale_w[j * 32 + k], s);
    sh = fmaf(c, shift_w[j * 32 + k], sh);
  }
  float a = s + 1.f;
  float b0 = (j < 32) ? 0.f : share1_b[j - 32];
  a_[t] = a;
  bias1[t] = fmaf(a, b0, sh);
  bias2[t] = (j < 32) ? 0.f : share2_b[j - 32];
}

// ---------- HDA chunk stage (512 threads): A 704 gran + W 1280 gran (both linear) ----------
// buffer: [0,11264) A (19x18 pos x 2 slots, pair-swizzled src); [11264,31744) W [t(20)][oc(64)]
__device__ __forceinline__ void hda_stage(const u16* __restrict__ asrc,
                                          const u16* __restrict__ wall,
                                          char* lb, int b, int by0, int bx0,
                                          int cc, int tid, int wid) {
  const u16* ap = asrc + (size_t)cc * PSP;
  const u16* wp = wall + (size_t)b * 40960 + cc * 10240;
  // A: 704 granules; content[g] = A[g ^ bit3(g)] (involution), dest linear
#pragma unroll
  for (int it = 0; it < 2; ++it) {
    if (it == 0 || tid < 192) {  // waves 0..2 for the tail (wave-uniform)
      int g = it * 512 + tid;
      int i = g ^ ((g >> 3) & 1);
      int pos = i >> 1, sl = i & 1;
      if (pos >= 342) { pos = 0; sl = 0; }
      int yy = pos / 18, xx = pos - yy * 18;
      const u16* src = ap + (((size_t)b * 258 + by0 + yy) * 258 + bx0 + xx) * 16 + sl * 8;
      __builtin_amdgcn_global_load_lds(GPTR(src),
          LPTR(lb + (it * 512 + wid * 64) * 16), 16, 0, 0);
    }
  }
  // W: 1280 granules = 2*512 + 256; src and dest both linear (t-major prep)
#pragma unroll
  for (int it = 0; it < 3; ++it) {
    if (it < 2 || tid < 256) {  // waves 0..3 for the tail (wave-uniform)
      int g = it * 512 + tid;
      __builtin_amdgcn_global_load_lds(GPTR(wp + g * 8),
          LPTR(lb + 11264 + (it * 512 + wid * 64) * 16), 16, 0, 0);
    }
  }
}

// ---------- HDA conv 3x3 s1 p1 64->64, MFMA, 4 chunks of 16 ic ----------
// R16 structure (best measured) + R19's verified conflict-free t-major W layout:
// 512 threads / 8 waves x 2 rows, acc[2][4]=32 AGPR, double-buffered DMA (63.5KB LDS,
// 2 blocks/CU), setprio around MFMA. W read (t*64+oc) granules -> bank residue = col%8
// -> 0 conflicts (R19-measured). launch_bounds(512,2); VGPR ~56, no spill.
// STAGE 1: dst = padded 4-plane bf16 relu(conv+bias), ic' = col*4+nf -> 8B stores
// STAGE 2: dst = NCHW f32 resid+conv+bias (weights pre-permuted to match plane order)
template <int STAGE>
__global__ __launch_bounds__(512, 2) void k_hda_mfma(const u16* __restrict__ asrc,
    const u16* __restrict__ wall, const float* __restrict__ bias,
    const float* __restrict__ resid, void* __restrict__ dst) {
  __shared__ char lds[63488];  // 2 x 31744
  const int wg0 = blockIdx.x;
  const int wg = ((wg0 & 7) << 8) + (wg0 >> 3);
  const int b = wg >> 8;
  const int rr = wg & 255;
  const int by0 = (rr >> 4) << 4, bx0 = (rr & 15) << 4;
  const int tid = threadIdx.x, lane = tid & 63, wid = tid >> 6;  // wid 0..7
  const int col = lane & 15, kq = lane >> 4;
  const int hi = kq >> 1, sl2 = kq & 1;
  f32x4 acc[2][4];
#pragma unroll
  for (int i = 0; i < 2; ++i)
#pragma unroll
    for (int j = 0; j < 4; ++j) acc[i][j] = 0.f;
  hda_stage(asrc, wall, lds, b, by0, bx0, 0, tid, wid);
#pragma unroll
  for (int cc = 0; cc < 4; ++cc) {
    __syncthreads();  // drains DMA for buf[cc&1]; prior reads of buf[(cc+1)&1] done
    if (cc < 3)
      hda_stage(asrc, wall, lds + ((cc + 1) & 1) * 31744, b, by0, bx0, cc + 1, tid, wid);
    const char* lb = lds + (cc & 1) * 31744;
    __builtin_amdgcn_s_setprio(1);
#pragma unroll
    for (int s = 0; s < 5; ++s) {  // tap = 2s + hi  (tap 9 = zero pad)
      const int t0 = 2 * s, t1 = 2 * s + 1;
      const int d0 = (t0 / 3) * 18 + (t0 % 3);
      const int d1 = (t1 / 3) * 18 + (t1 % 3);
      const int dd = hi ? d1 : d0;
      bf16x8 a[2];
#pragma unroll
      for (int mf = 0; mf < 2; ++mf) {
        int pos = (wid * 2 + mf) * 18 + col + dd;
        int g = (pos * 2 + sl2) ^ ((pos >> 2) & 1);
        a[mf] = __builtin_bit_cast(bf16x8, *(const u16x8*)(lb + g * 16));
      }
      bf16x8 w[4];
#pragma unroll
      for (int nf = 0; nf < 4; ++nf)
        w[nf] = __builtin_bit_cast(bf16x8,
            *(const u16x8*)(lb + 11264 + ((s * 4 + kq) * 64 + nf * 16 + col) * 16));
#pragma unroll
      for (int mf = 0; mf < 2; ++mf)
#pragma unroll
        for (int nf = 0; nf < 4; ++nf) acc[mf][nf] = mfma16(a[mf], w[nf], acc[mf][nf]);
    }
    __builtin_amdgcn_s_setprio(0);
  }
  const float* bb = bias + b * 64;
#pragma unroll
  for (int mf = 0; mf < 2; ++mf) {
    int y = by0 + wid * 2 + mf;
    if (STAGE == 1) {
#pragma unroll
      for (int r = 0; r < 4; ++r) {
        int x = bx0 + kq * 4 + r;
        u32x2 pk;
        pk[0] = (u32)f2bf(fmaxf(acc[mf][0][r] + bb[col], 0.f)) |
                ((u32)f2bf(fmaxf(acc[mf][1][r] + bb[16 + col], 0.f)) << 16);
        pk[1] = (u32)f2bf(fmaxf(acc[mf][2][r] + bb[32 + col], 0.f)) |
                ((u32)f2bf(fmaxf(acc[mf][3][r] + bb[48 + col], 0.f)) << 16);
        *(u32x2*)((u16*)dst + (size_t)(col >> 2) * PSP +
                  (((size_t)b * 258 + y + 1) * 258 + x + 1) * 16 + (col & 3) * 4) = pk;
      }
    } else {
#pragma unroll
      for (int nf = 0; nf < 4; ++nf) {
        int oc = nf * 16 + col;
        float bv = bb[oc];
        size_t o = (((size_t)b * 64 + oc) * 256 + y) * 256 + bx0 + kq * 4;
        f32x4 rx = *(const f32x4*)(resid + o);
        f32x4 vv;
#pragma unroll
        for (int r = 0; r < 4; ++r) vv[r] = rx[r] + acc[mf][nf][r] + bv;
        *(f32x4*)((float*)dst + o) = vv;
      }
    }
  }
}

extern "C" void kernel_launch(void* const* d_in, const int* in_sizes, int n_in,
                              void* d_out, int out_size, void* d_ws, size_t ws_size,
                              hipStream_t stream) {
  const float* x        = (const float*)d_in[0];
  const float* ow1      = (const float*)d_in[1];
  const float* ow2      = (const float*)d_in[2];
  const float* cw1      = (const float*)d_in[3];
  const float* cb1      = (const float*)d_in[4];
  const float* cw2      = (const float*)d_in[5];
  const float* cb2      = (const float*)d_in[6];
  const float* cw3      = (const float*)d_in[7];
  const float* cb3      = (const float*)d_in[8];
  const float* scale_w  = (const float*)d_in[9];
  const float* scale_b  = (const float*)d_in[10];
  const float* shift_w  = (const float*)d_in[11];
  const float* shift_b  = (const float*)d_in[12];
  const float* dyn1     = (const float*)d_in[13];
  const float* share1   = (const float*)d_in[14];
  const float* share1_b = (const float*)d_in[15];
  const float* dyn2     = (const float*)d_in[16];
  const float* share2   = (const float*)d_in[17];
  const float* share2_b = (const float*)d_in[18];
  float* out = (float*)d_out;

  char* p = (char*)d_ws;
  u16* xh   = (u16*)p;            p += PSP * 4 * 2;   // 4 padded planes
  u16* midh = (u16*)p;            p += PSP * 4 * 2;   // 4 padded planes
  u16* wbf1 = (u16*)p;            p += (size_t)327680 * 2;
  u16* wbf2 = (u16*)p;            p += (size_t)327680 * 2;
  u16* cwb1 = (u16*)p;            p += (size_t)106496 * 2;
  u16* cwb2 = (u16*)p;            p += (size_t)32 * 288 * 2;
  u16* cwb3 = (u16*)p;            p += (size_t)32 * 288 * 2;
  float* a_    = (float*)p;       p += 512 * 4;
  float* bias1 = (float*)p;       p += 512 * 4;
  float* bias2 = (float*)p;       p += 512 * 4;
  float* cond  = (float*)p;       p += 256 * 4;
  // cond-net temporaries overlap midh (dead before midh border-zero + hda1)
  u16* h1h = midh;                                   // 8*126*126*32 bf16 (permuted ch)
  u16* h2h = h1h + (size_t)8 * 126 * 126 * 32;       // 8*63*63*32 bf16
  float* h3 = (float*)(h2h + (size_t)8 * 63 * 63 * 32);  // 8*32*32*32 f32

  k_zero_border<<<129, 256, 0, stream>>>(xh);
  k_tr<<<dim3(8, 256, 8), 256, 0, stream>>>(x, xh);

  k_prep_cw1<<<(106496 + 255) / 256, 256, 0, stream>>>(cw1, cwb1);
  k_prep_cw<<<(32 * 288 + 255) / 256, 256, 0, stream>>>(cw2, cwb2, 32, 9, 32 * 288, 1);
  k_prep_cw<<<(32 * 288 + 255) / 256, 256, 0, stream>>>(cw3, cwb3, 32, 9, 32 * 288, 0);

  k_cond1_mfma<<<512, 256, 0, stream>>>(xh, cwb1, cb1, h1h);
  k_conv_s2<126, 63, 32, 3, 0><<<dim3(4, 8, 8), 256, 0, stream>>>(h1h, cwb2, cb2, h2h);
  k_conv_s2<63, 32, 32, 3, 1><<<dim3(2, 4, 8), 256, 0, stream>>>(h2h, cwb3, cb3, h3);

  k_mean<<<256, 256, 0, stream>>>(h3, cond);
  k_film<<<1, 512, 0, stream>>>(cond, scale_w, scale_b, shift_w, shift_b,
                                share1_b, share2_b, a_, bias1, bias2);

  k_zero_border<<<129, 256, 0, stream>>>(midh);

  k_prep_hda<<<(327680 + 255) / 256, 256, 0, stream>>>(dyn1, ow1, share1, a_, wbf1, 1, 0);
  k_prep_hda<<<(327680 + 255) / 256, 256, 0, stream>>>(dyn2, ow2, share2, a_, wbf2, 0, 1);

  k_hda_mfma<1><<<2048, 512, 0, stream>>>(xh, wbf1, bias1, nullptr, midh);
  k_hda_mfma<2><<<2048, 512, 0, stream>>>(midh, wbf2, bias2, x, out);
}

// Round 21
// 248.467 us; speedup vs baseline: 1.3846x; 1.0033x over previous
//
#include <hip/hip_runtime.h>

typedef unsigned short u16;
typedef unsigned int u32;
typedef __attribute__((ext_vector_type(8))) __bf16 bf16x8;
typedef __attribute__((ext_vector_type(8))) u16 u16x8;
typedef __attribute__((ext_vector_type(4))) float f32x4;
typedef __attribute__((ext_vector_type(2))) u32 u32x2;

// padded plane: [b][258][258][16ic]; 1-pixel zero border for DMA staging
static constexpr size_t PSP = (size_t)8 * 258 * 258 * 16;  // u16 elems per plane

#define GPTR(p) ((const __attribute__((address_space(1))) void*)(p))
#define LPTR(p) ((__attribute__((address_space(3))) void*)(p))

__device__ __forceinline__ u16 f2bf(float f) {
  u32 u = __builtin_bit_cast(u32, f);
  u = (u + 0x7FFFu + ((u >> 16) & 1u)) >> 16;
  return (u16)u;
}

__device__ __forceinline__ f32x4 mfma16(bf16x8 a, bf16x8 b, f32x4 c) {
  return __builtin_amdgcn_mfma_f32_16x16x32_bf16(a, b, c, 0, 0, 0);
}

// ---------- zero the 1-pixel border of a 4-plane padded array ----------
__global__ void k_zero_border(u16* __restrict__ base) {
  int idx = blockIdx.x * 256 + threadIdx.x;
  if (idx >= 4 * 8 * 1028) return;
  int p = idx / (8 * 1028), r = idx - p * (8 * 1028);
  int b = r / 1028, e = r - b * 1028;
  int y, x;
  if (e < 258) { y = 0; x = e; }
  else if (e < 516) { y = 257; x = e - 258; }
  else { int e2 = e - 516; y = 1 + (e2 >> 1); x = (e2 & 1) * 257; }
  u16* d = base + (size_t)p * PSP + (((size_t)b * 258 + y) * 258 + x) * 16;
  u16x8 z = (u16x8)0;
  *(u16x8*)d = z;
  *(u16x8*)(d + 8) = z;
}

// ---------- NCHW f32 -> 4-plane padded bf16: [p][b][1+y][1+x][16ic] ----------
__global__ __launch_bounds__(256) void k_tr(const float* __restrict__ x,
                                            u16* __restrict__ xh) {
  __shared__ float t[64][33];
  const int b = blockIdx.z, y = blockIdx.y, x0 = blockIdx.x * 32;
  const int tid = threadIdx.x;
  {
    int ic = tid >> 2, xo = (tid & 3) * 8;
    const float* s = x + (((size_t)b * 64 + ic) * 256 + y) * 256 + x0 + xo;
    f32x4 v0 = *(const f32x4*)s;
    f32x4 v1 = *(const f32x4*)(s + 4);
#pragma unroll
    for (int j = 0; j < 4; ++j) { t[ic][xo + j] = v0[j]; t[ic][xo + 4 + j] = v1[j]; }
  }
  __syncthreads();
  {
    int xc = tid & 31, slot = tid >> 5;  // slot 0..7 -> ic0 = slot*8
    int ic0 = slot * 8;
    u16x8 v;
#pragma unroll
    for (int j = 0; j < 8; ++j) v[j] = f2bf(t[ic0 + j][xc]);
    *(u16x8*)(xh + (size_t)(slot >> 1) * PSP +
              (((size_t)b * 258 + y + 1) * 258 + x0 + xc + 1) * 16 + (slot & 1) * 8) = v;
  }
}

// ---------- conv2/3 weights: [OC][IC][3][3] f32 -> [oc][tap*IC+icp] bf16 ----------
// perm=1: input channels arrive permuted as icp = (ic&15)*2 + (ic>>4)  (IC=32)
__global__ void k_prep_cw(const float* __restrict__ src, u16* __restrict__ dst,
                          int IC, int KK2, int n, int perm) {
  int d = blockIdx.x * 256 + threadIdx.x;
  if (d >= n) return;
  int per = KK2 * IC;
  int oc = d / per, r = d - oc * per;
  int tap = r / IC, icp = r - tap * IC;
  int ic = perm ? ((icp >> 1) + (icp & 1) * 16) : icp;
  dst[d] = f2bf(src[(oc * IC + ic) * KK2 + tap]);
}

// ---------- conv1 weights: [32][64][7][7] f32 -> [8 chunks][t(52)][oc(32)][8 ic] bf16 ----------
// t-major so DMA dests are linear; taps 49..51 zero-padded; chunk h = ic h*8..h*8+7
__global__ void k_prep_cw1(const float* __restrict__ src, u16* __restrict__ dst) {
  int d = blockIdx.x * 256 + threadIdx.x;  // 8*52*32*8 = 106496
  if (d >= 106496) return;
  int h = d / 13312, r = d - h * 13312;
  int t = r >> 8, r2 = r & 255;
  int oc = r2 >> 3, i = r2 & 7;
  float v = (t < 49) ? src[(oc * 64 + h * 8 + i) * 49 + t] : 0.f;
  dst[d] = f2bf(v);
}

// ---------- HDA weights -> [b][cc(4)][t(20)][oc(64)][j(8)] bf16 (t-major, conflict-free) ----------
// t = s*4+kq: tap = 2s + (kq>>1) (tap 9 zero-pad); ic-slot icp = cc*16 + (kq&1)*8 + j.
// perm=1 (stage 2): slot icp holds real channel ic = (icp&3)*16 + (icp>>2)
__global__ void k_prep_hda(const float* __restrict__ dyn, const float* __restrict__ ow,
                           const float* __restrict__ share, const float* __restrict__ a_,
                           u16* __restrict__ dst, int use_a, int perm) {
  int d = blockIdx.x * 256 + threadIdx.x;  // 8*4*20*64*8 = 327680
  if (d >= 327680) return;
  int b = d / 40960, r = d - b * 40960;
  int cc = r / 10240, r2 = r - cc * 10240;
  int t = r2 / 512, r3 = r2 - t * 512;
  int oc = r3 >> 3, j = r3 & 7;
  int s = t >> 2, kq = t & 3;
  int tap = 2 * s + (kq >> 1);
  float v = 0.f;
  if (tap < 9) {
    int icp = cc * 16 + (kq & 1) * 8 + j;
    int ic = perm ? ((icp & 3) * 16 + (icp >> 2)) : icp;
    v = (oc < 32) ? dyn[(oc * 64 + ic) * 9 + tap] * ow[((b * 32 + oc) * 64 + ic) * 9 + tap]
                  : share[((oc - 32) * 64 + ic) * 9 + tap];
    if (use_a) v *= a_[b * 64 + oc];
  }
  dst[d] = f2bf(v);
}

// ---------- cond conv1: 7x7 s2 p1 64->32, MFMA, DMA-staged A+W in LDS ----------
__global__ __launch_bounds__(256, 2) void k_cond1_mfma(const u16* __restrict__ xh,
    const u16* __restrict__ wp /*[8][52][32][8]*/, const float* __restrict__ cb,
    u16* __restrict__ dst) {
  __shared__ char lds[49152];  // [0,22528): A; [22528,49152): W
  const int wg0 = blockIdx.x;
  const int wg = ((wg0 & 7) << 6) | (wg0 >> 3);
  const int b = wg >> 6, rr = wg & 63;
  const int oh0 = (rr >> 3) << 4, ow0 = (rr & 7) << 4;
  const int tid = threadIdx.x, lane = tid & 63, wid = tid >> 6;
  const int col = lane & 15, kq = lane >> 4;
  f32x4 acc[4][2];
#pragma unroll
  for (int i = 0; i < 4; ++i)
#pragma unroll
    for (int j = 0; j < 2; ++j) acc[i][j] = 0.f;
  int pb[4];
#pragma unroll
  for (int mf = 0; mf < 4; ++mf) pb[mf] = (2 * (wid * 4 + mf)) * 37 + 2 * col;
#pragma unroll 1
  for (int h = 0; h < 8; ++h) {
    __syncthreads();
    // A DMA: granule g holds A[swz(g)]; source pre-swizzled, dest linear
#pragma unroll
    for (int it = 0; it < 6; ++it) {
      if (it < 5 || wid < 2) {
        int g = it * 256 + tid;
        int i = g ^ ((g >> 3) & 7);
        if (i >= 1406) i = 0;  // dummy granules (never read)
        int r = i / 37, cc2 = i - r * 37;
        const u16* src = xh + (size_t)(h >> 1) * PSP +
            (((size_t)b * 258 + 2 * oh0 + r) * 258 + 2 * ow0 + cc2) * 16 + (h & 1) * 8;
        __builtin_amdgcn_global_load_lds(GPTR(src),
            LPTR(lds + (it * 256 + wid * 64) * 16), 16, 0, 0);
      }
    }
    // W DMA: [t(52)][oc(32)] linear dest
#pragma unroll
    for (int it = 0; it < 7; ++it) {
      if (it < 6 || wid < 2) {
        int g = it * 256 + tid;
        int t = g >> 5, oc = g & 31;
        const u16* src = wp + h * 13312 + t * 256 + oc * 8;
        __builtin_amdgcn_global_load_lds(GPTR(src),
            LPTR(lds + 22528 + (it * 256 + wid * 64) * 16), 16, 0, 0);
      }
    }
    __syncthreads();
    __builtin_amdgcn_s_setprio(1);
#pragma unroll
    for (int s = 0; s < 13; ++s) {  // taps 4s+kq
      const int t0 = 4 * s;
      const int kh0 = t0 / 7, r7 = t0 % 7;
      int carry = (kq >= 7 - r7) ? 1 : 0;
      int kh = kh0 + carry;
      int kw = r7 + kq - carry * 7;
      int prow = kh * 37 + kw;
      bf16x8 a[4];
#pragma unroll
      for (int mf = 0; mf < 4; ++mf) {
        int pos = pb[mf] + prow;
        int g = pos ^ ((pos >> 3) & 7);
        a[mf] = __builtin_bit_cast(bf16x8, *(const u16x8*)(lds + g * 16));
      }
      bf16x8 w[2];
#pragma unroll
      for (int nf = 0; nf < 2; ++nf)
        w[nf] = __builtin_bit_cast(bf16x8,
            *(const u16x8*)(lds + 22528 + (((4 * s + kq) * 32) + nf * 16 + col) * 16));
#pragma unroll
      for (int mf = 0; mf < 4; ++mf)
#pragma unroll
        for (int nf = 0; nf < 2; ++nf) acc[mf][nf] = mfma16(a[mf], w[nf], acc[mf][nf]);
    }
    __builtin_amdgcn_s_setprio(0);
  }
  const float bv0 = cb[col], bv1 = cb[16 + col];
#pragma unroll
  for (int mf = 0; mf < 4; ++mf) {
    int oh = oh0 + wid * 4 + mf;
    if (oh >= 126) continue;
#pragma unroll
    for (int r = 0; r < 4; ++r) {
      int ow = ow0 + kq * 4 + r;
      if (ow >= 126) continue;
      u32 pack = (u32)f2bf(fmaxf(acc[mf][0][r] + bv0, 0.f)) |
                 ((u32)f2bf(fmaxf(acc[mf][1][r] + bv1, 0.f)) << 16);
      *(u32*)(dst + (((size_t)b * 126 + oh) * 126 + ow) * 32 + col * 2) = pack;
    }
  }
}

// ---------- generic stride-2 pad-1 conv (small conv2/conv3) ----------
template <int HI, int HO, int IC, int KK, int OUTF32>
__global__ __launch_bounds__(256, 4) void k_conv_s2(const u16* __restrict__ src,
    const u16* __restrict__ wgt, const float* __restrict__ bias, void* __restrict__ dst) {
  const int b = blockIdx.z;
  const int by0 = blockIdx.y * 8, bx0 = blockIdx.x * 16;
  const int tid = threadIdx.x, lane = tid & 63, wid = tid >> 6;
  const int col = lane & 15, kq = lane >> 4;
  f32x4 acc[2][2];
#pragma unroll
  for (int i = 0; i < 2; ++i)
#pragma unroll
    for (int j = 0; j < 2; ++j) acc[i][j] = 0.f;
  const u16x8 Z = (u16x8)0;
#pragma unroll
  for (int kh = 0; kh < KK; ++kh) {
#pragma unroll
    for (int kw = 0; kw < KK; ++kw) {
#pragma unroll
      for (int h = 0; h < IC / 32; ++h) {
        bf16x8 a[2];
#pragma unroll
        for (int mf = 0; mf < 2; ++mf) {
          int oh = by0 + wid * 2 + mf;
          int ih = 2 * oh - 1 + kh;
          int ix = 2 * (bx0 + col) - 1 + kw;
          int ic = h * 32 + kq * 8;
          u16x8 raw = Z;
          if ((unsigned)ih < (unsigned)HI && (unsigned)ix < (unsigned)HI)
            raw = *(const u16x8*)(src + (((size_t)b * HI + ih) * HI + ix) * IC + ic);
          a[mf] = __builtin_bit_cast(bf16x8, raw);
        }
        int k0 = (kh * KK + kw) * IC + h * 32 + kq * 8;
        bf16x8 w[2];
#pragma unroll
        for (int nf = 0; nf < 2; ++nf)
          w[nf] = __builtin_bit_cast(bf16x8,
                    *(const u16x8*)(wgt + (size_t)(nf * 16 + col) * (KK * KK * IC) + k0));
#pragma unroll
        for (int mf = 0; mf < 2; ++mf)
#pragma unroll
          for (int nf = 0; nf < 2; ++nf) acc[mf][nf] = mfma16(a[mf], w[nf], acc[mf][nf]);
      }
    }
  }
#pragma unroll
  for (int mf = 0; mf < 2; ++mf) {
    int oh = by0 + wid * 2 + mf;
    if (oh >= HO) continue;
#pragma unroll
    for (int nf = 0; nf < 2; ++nf) {
      int oc = nf * 16 + col;
      float bv = bias[oc];
#pragma unroll
      for (int r = 0; r < 4; ++r) {
        int ow = bx0 + kq * 4 + r;
        if (ow >= HO) continue;
        float v = fmaxf(acc[mf][nf][r] + bv, 0.f);
        if (OUTF32)
          ((float*)dst)[(((size_t)b * 32 + oc) * HO + oh) * HO + ow] = v;
        else
          ((u16*)dst)[(((size_t)b * HO + oh) * HO + ow) * 32 + oc] = f2bf(v);
      }
    }
  }
}

// ---------- mean over 32x32 -> cond[8*32] ----------
__global__ void k_mean(const float* __restrict__ h3, float* __restrict__ cond) {
  int bo = blockIdx.x;
  int tid = threadIdx.x;
  float s = 0.f;
  for (int i = tid; i < 1024; i += 256) s += h3[bo * 1024 + i];
  __shared__ float red[256];
  red[tid] = s;
  __syncthreads();
  for (int o = 128; o > 0; o >>= 1) {
    if (tid < o) red[tid] += red[tid + o];
    __syncthreads();
  }
  if (tid == 0) cond[bo] = red[0] * (1.f / 1024.f);
}

// ---------- FiLM fold ----------
__global__ void k_film(const float* __restrict__ cond,
                       const float* __restrict__ scale_w, const float* __restrict__ scale_b,
                       const float* __restrict__ shift_w, const float* __restrict__ shift_b,
                       const float* __restrict__ share1_b, const float* __restrict__ share2_b,
                       float* __restrict__ a_, float* __restrict__ bias1,
                       float* __restrict__ bias2) {
  int t = threadIdx.x;  // 512
  int b = t >> 6, j = t & 63;
  float s = scale_b[j], sh = shift_b[j];
  for (int k = 0; k < 32; ++k) {
    float c = cond[b * 32 + k];
    s = fmaf(c, scale_w[j * 32 + k], s);
    sh = fmaf(c, shift_w[j * 32 + k], sh);
  }
  float a = s + 1.f;
  float b0 = (j < 32) ? 0.f : share1_b[j - 32];
  a_[t] = a;
  bias1[t] = fmaf(a, b0, sh);
  bias2[t] = (j < 32) ? 0.f : share2_b[j - 32];
}

// ---------- HDA chunk stage (512 threads): A 704 gran + W 1280 gran (both linear) ----------
// buffer: [0,11264) A (19x18 pos x 2 slots, pair-swizzled src); [11264,31744) W [t(20)][oc(64)]
__device__ __forceinline__ void hda_stage(const u16* __restrict__ asrc,
                                          const u16* __restrict__ wall,
                                          char* lb, int b, int by0, int bx0,
                                          int cc, int tid, int wid) {
  const u16* ap = asrc + (size_t)cc * PSP;
  const u16* wp = wall + (size_t)b * 40960 + cc * 10240;
  // A: 704 granules; content[g] = A[g ^ bit3(g)] (involution), dest linear
#pragma unroll
  for (int it = 0; it < 2; ++it) {
    if (it == 0 || tid < 192) {  // waves 0..2 for the tail (wave-uniform)
      int g = it * 512 + tid;
      int i = g ^ ((g >> 3) & 1);
      int pos = i >> 1, sl = i & 1;
      if (pos >= 342) { pos = 0; sl = 0; }
      int yy = pos / 18, xx = pos - yy * 18;
      const u16* src = ap + (((size_t)b * 258 + by0 + yy) * 258 + bx0 + xx) * 16 + sl * 8;
      __builtin_amdgcn_global_load_lds(GPTR(src),
          LPTR(lb + (it * 512 + wid * 64) * 16), 16, 0, 0);
    }
  }
  // W: 1280 granules = 2*512 + 256; src and dest both linear (t-major prep)
#pragma unroll
  for (int it = 0; it < 3; ++it) {
    if (it < 2 || tid < 256) {  // waves 0..3 for the tail (wave-uniform)
      int g = it * 512 + tid;
      __builtin_amdgcn_global_load_lds(GPTR(wp + g * 8),
          LPTR(lb + 11264 + (it * 512 + wid * 64) * 16), 16, 0, 0);
    }
  }
}

// ---------- HDA conv 3x3 s1 p1 64->64, MFMA, 4 chunks of 16 ic ----------
// R20 structure (conflict-free t-major W). NEW: stage-1 epilogue bounces acc through
// LDS ([16y][16x][64ch], 32KB, buffers dead after K-loop) so global stores become
// 4 x 256B contiguous runs per wave -> fixes the measured 2x HBM write amplification
// (R20: WRITE_SIZE 132MB for 68MB output; 8B/lane scattered stores = 32B transactions).
// STAGE 1: dst = padded 4-plane bf16 relu(conv+bias), ic' = col*4+nf
// STAGE 2: dst = NCHW f32 resid+conv+bias (weights pre-permuted to match plane order)
template <int STAGE>
__global__ __launch_bounds__(512, 2) void k_hda_mfma(const u16* __restrict__ asrc,
    const u16* __restrict__ wall, const float* __restrict__ bias,
    const float* __restrict__ resid, void* __restrict__ dst) {
  __shared__ char lds[63488];  // 2 x 31744
  const int wg0 = blockIdx.x;
  const int wg = ((wg0 & 7) << 8) + (wg0 >> 3);
  const int b = wg >> 8;
  const int rr = wg & 255;
  const int by0 = (rr >> 4) << 4, bx0 = (rr & 15) << 4;
  const int tid = threadIdx.x, lane = tid & 63, wid = tid >> 6;  // wid 0..7
  const int col = lane & 15, kq = lane >> 4;
  const int hi = kq >> 1, sl2 = kq & 1;
  f32x4 acc[2][4];
#pragma unroll
  for (int i = 0; i < 2; ++i)
#pragma unroll
    for (int j = 0; j < 4; ++j) acc[i][j] = 0.f;
  hda_stage(asrc, wall, lds, b, by0, bx0, 0, tid, wid);
#pragma unroll
  for (int cc = 0; cc < 4; ++cc) {
    __syncthreads();  // drains DMA for buf[cc&1]; prior reads of buf[(cc+1)&1] done
    if (cc < 3)
      hda_stage(asrc, wall, lds + ((cc + 1) & 1) * 31744, b, by0, bx0, cc + 1, tid, wid);
    const char* lb = lds + (cc & 1) * 31744;
    __builtin_amdgcn_s_setprio(1);
#pragma unroll
    for (int s = 0; s < 5; ++s) {  // tap = 2s + hi  (tap 9 = zero pad)
      const int t0 = 2 * s, t1 = 2 * s + 1;
      const int d0 = (t0 / 3) * 18 + (t0 % 3);
      const int d1 = (t1 / 3) * 18 + (t1 % 3);
      const int dd = hi ? d1 : d0;
      bf16x8 a[2];
#pragma unroll
      for (int mf = 0; mf < 2; ++mf) {
        int pos = (wid * 2 + mf) * 18 + col + dd;
        int g = (pos * 2 + sl2) ^ ((pos >> 2) & 1);
        a[mf] = __builtin_bit_cast(bf16x8, *(const u16x8*)(lb + g * 16));
      }
      bf16x8 w[4];
#pragma unroll
      for (int nf = 0; nf < 4; ++nf)
        w[nf] = __builtin_bit_cast(bf16x8,
            *(const u16x8*)(lb + 11264 + ((s * 4 + kq) * 64 + nf * 16 + col) * 16));
#pragma unroll
      for (int mf = 0; mf < 2; ++mf)
#pragma unroll
        for (int nf = 0; nf < 4; ++nf) acc[mf][nf] = mfma16(a[mf], w[nf], acc[mf][nf]);
    }
    __builtin_amdgcn_s_setprio(0);
  }
  const float* bb = bias + b * 64;
  if (STAGE == 1) {
    // ---- LDS-bounce epilogue: [y(16)][x(16)][64ch] bf16 = 32KB ----
    __syncthreads();  // all K-loop LDS reads done before overwrite
#pragma unroll
    for (int mf = 0; mf < 2; ++mf) {
      int yl = wid * 2 + mf;
#pragma unroll
      for (int r = 0; r < 4; ++r) {
        int xl = kq * 4 + r;
        u32x2 pk;
        pk[0] = (u32)f2bf(fmaxf(acc[mf][0][r] + bb[col], 0.f)) |
                ((u32)f2bf(fmaxf(acc[mf][1][r] + bb[16 + col], 0.f)) << 16);
        pk[1] = (u32)f2bf(fmaxf(acc[mf][2][r] + bb[32 + col], 0.f)) |
                ((u32)f2bf(fmaxf(acc[mf][3][r] + bb[48 + col], 0.f)) << 16);
        *(u32x2*)(lds + (yl * 16 + xl) * 128 + col * 8) = pk;
      }
    }
    __syncthreads();
    // coalesced store: granule g = (y*16+x)*8 + q; q = plane*2 + half
    // per wave: 8 consecutive pixels x 8 q -> 4 planes x 256B contiguous runs
#pragma unroll
    for (int it = 0; it < 4; ++it) {
      int g = it * 512 + tid;
      int q = g & 7, xl = (g >> 3) & 15, yl = g >> 7;
      int p = q >> 1, half = q & 1;
      u16x8 v = *(const u16x8*)(lds + g * 16);  // linear: (yl*16+xl)*128 + q*16
      *(u16x8*)((u16*)dst + (size_t)p * PSP +
                (((size_t)b * 258 + by0 + yl + 1) * 258 + bx0 + xl + 1) * 16 + half * 8) = v;
    }
  } else {
#pragma unroll
    for (int mf = 0; mf < 2; ++mf) {
      int y = by0 + wid * 2 + mf;
#pragma unroll
      for (int nf = 0; nf < 4; ++nf) {
        int oc = nf * 16 + col;
        float bv = bb[oc];
        size_t o = (((size_t)b * 64 + oc) * 256 + y) * 256 + bx0 + kq * 4;
        f32x4 rx = *(const f32x4*)(resid + o);
        f32x4 vv;
#pragma unroll
        for (int r = 0; r < 4; ++r) vv[r] = rx[r] + acc[mf][nf][r] + bv;
        *(f32x4*)((float*)dst + o) = vv;
      }
    }
  }
}

extern "C" void kernel_launch(void* const* d_in, const int* in_sizes, int n_in,
                              void* d_out, int out_size, void* d_ws, size_t ws_size,
                              hipStream_t stream) {
  const float* x        = (const float*)d_in[0];
  const float* ow1      = (const float*)d_in[1];
  const float* ow2      = (const float*)d_in[2];
  const float* cw1      = (const float*)d_in[3];
  const float* cb1      = (const float*)d_in[4];
  const float* cw2      = (const float*)d_in[5];
  const float* cb2      = (const float*)d_in[6];
  const float* cw3      = (const float*)d_in[7];
  const float* cb3      = (const float*)d_in[8];
  const float* scale_w  = (const float*)d_in[9];
  const float* scale_b  = (const float*)d_in[10];
  const float* shift_w  = (const float*)d_in[11];
  const float* shift_b  = (const float*)d_in[12];
  const float* dyn1     = (const float*)d_in[13];
  const float* share1   = (const float*)d_in[14];
  const float* share1_b = (const float*)d_in[15];
  const float* dyn2     = (const float*)d_in[16];
  const float* share2   = (const float*)d_in[17];
  const float* share2_b = (const float*)d_in[18];
  float* out = (float*)d_out;

  char* p = (char*)d_ws;
  u16* xh   = (u16*)p;            p += PSP * 4 * 2;   // 4 padded planes
  u16* midh = (u16*)p;            p += PSP * 4 * 2;   // 4 padded planes
  u16* wbf1 = (u16*)p;            p += (size_t)327680 * 2;
  u16* wbf2 = (u16*)p;            p += (size_t)327680 * 2;
  u16* cwb1 = (u16*)p;            p += (size_t)106496 * 2;
  u16* cwb2 = (u16*)p;            p += (size_t)32 * 288 * 2;
  u16* cwb3 = (u16*)p;            p += (size_t)32 * 288 * 2;
  float* a_    = (float*)p;       p += 512 * 4;
  float* bias1 = (float*)p;       p += 512 * 4;
  float* bias2 = (float*)p;       p += 512 * 4;
  float* cond  = (float*)p;       p += 256 * 4;
  // cond-net temporaries overlap midh (dead before midh border-zero + hda1)
  u16* h1h = midh;                                   // 8*126*126*32 bf16 (permuted ch)
  u16* h2h = h1h + (size_t)8 * 126 * 126 * 32;       // 8*63*63*32 bf16
  float* h3 = (float*)(h2h + (size_t)8 * 63 * 63 * 32);  // 8*32*32*32 f32

  k_zero_border<<<129, 256, 0, stream>>>(xh);
  k_tr<<<dim3(8, 256, 8), 256, 0, stream>>>(x, xh);

  k_prep_cw1<<<(106496 + 255) / 256, 256, 0, stream>>>(cw1, cwb1);
  k_prep_cw<<<(32 * 288 + 255) / 256, 256, 0, stream>>>(cw2, cwb2, 32, 9, 32 * 288, 1);
  k_prep_cw<<<(32 * 288 + 255) / 256, 256, 0, stream>>>(cw3, cwb3, 32, 9, 32 * 288, 0);

  k_cond1_mfma<<<512, 256, 0, stream>>>(xh, cwb1, cb1, h1h);
  k_conv_s2<126, 63, 32, 3, 0><<<dim3(4, 8, 8), 256, 0, stream>>>(h1h, cwb2, cb2, h2h);
  k_conv_s2<63, 32, 32, 3, 1><<<dim3(2, 4, 8), 256, 0, stream>>>(h2h, cwb3, cb3, h3);

  k_mean<<<256, 256, 0, stream>>>(h3, cond);
  k_film<<<1, 512, 0, stream>>>(cond, scale_w, scale_b, shift_w, shift_b,
                                share1_b, share2_b, a_, bias1, bias2);

  k_zero_border<<<129, 256, 0, stream>>>(midh);

  k_prep_hda<<<(327680 + 255) / 256, 256, 0, stream>>>(dyn1, ow1, share1, a_, wbf1, 1, 0);
  k_prep_hda<<<(327680 + 255) / 256, 256, 0, stream>>>(dyn2, ow2, share2, a_, wbf2, 0, 1);

  k_hda_mfma<1><<<2048, 512, 0, stream>>>(xh, wbf1, bias1, nullptr, midh);
  k_hda_mfma<2><<<2048, 512, 0, stream>>>(midh, wbf2, bias2, x, out);
}